// Round 3
// baseline (4067.143 us; speedup 1.0000x reference)
//
#include <hip/hip_runtime.h>
#include <math.h>

// ---------------- problem constants ----------------
#define BB    32
#define C_IN  3
#define H0    256
#define W0    256
#define C1    32          // conv1 out: (B,32,128,128)
#define H1    128
#define W1    128
#define C2    64          // conv2 out: (B,64,64,64)
#define H2    64
#define W2    64
#define HW2   (H2*W2)     // 4096
#define N_EMB 512
#define E_DIM 64
#define NZ    (BB*C2*HW2) // 8388608

// ---------------- conv1: 3->32, k4 s2 p1, ReLU (oc split x2) ----------------
__global__ __launch_bounds__(256) void conv1_kernel(const float* __restrict__ x,
        const float* __restrict__ w, const float* __restrict__ bias,
        float* __restrict__ out) {
    int t = blockIdx.x * 256 + threadIdx.x;           // G*128*128*2 threads
    int ox  = t & (W1 - 1);
    int oy  = (t >> 7) & (H1 - 1);
    int ocg = (t >> 14) & 1;
    int b   = t >> 15;
    const float* xb = x + (size_t)b * (C_IN * H0 * W0);
    float v[48];
    #pragma unroll
    for (int ic = 0; ic < 3; ++ic)
        #pragma unroll
        for (int dy = 0; dy < 4; ++dy) {
            int iy = oy * 2 - 1 + dy;
            #pragma unroll
            for (int dx = 0; dx < 4; ++dx) {
                int ix = ox * 2 - 1 + dx;
                float val = 0.f;
                if ((unsigned)iy < H0 && (unsigned)ix < W0)
                    val = xb[((size_t)ic * H0 + iy) * W0 + ix];
                v[(ic * 4 + dy) * 4 + dx] = val;
            }
        }
    float* ob = out + ((size_t)b * C1 + ocg * 16) * (H1 * W1) + (size_t)oy * W1 + ox;
    #pragma unroll
    for (int j = 0; j < 16; ++j) {
        int oc = ocg * 16 + j;
        float a = bias[oc];
        #pragma unroll
        for (int k = 0; k < 48; ++k) a = fmaf(v[k], w[oc * 48 + k], a);
        ob[(size_t)j * (H1 * W1)] = fmaxf(a, 0.f);
    }
}

// ---------------- conv2: 32->64, k4 s2 p1, ReLU (oc split x4) ----------------
__global__ __launch_bounds__(256) void conv2_kernel(const float* __restrict__ in,
        const float* __restrict__ w, const float* __restrict__ bias,
        float* __restrict__ out) {
    int t = blockIdx.x * 256 + threadIdx.x;           // G*64*64*4 threads
    int ox  = t & (W2 - 1);
    int oy  = (t >> 6) & (H2 - 1);
    int ocg = (t >> 12) & 3;
    int b   = t >> 14;
    float acc[16];
    #pragma unroll
    for (int j = 0; j < 16; ++j) acc[j] = bias[ocg * 16 + j];
    const float* ib = in + (size_t)b * (C1 * H1 * W1);
    for (int ic = 0; ic < 32; ++ic) {
        float v[16];
        #pragma unroll
        for (int dy = 0; dy < 4; ++dy) {
            int iy = oy * 2 - 1 + dy;
            #pragma unroll
            for (int dx = 0; dx < 4; ++dx) {
                int ix = ox * 2 - 1 + dx;
                float val = 0.f;
                if ((unsigned)iy < H1 && (unsigned)ix < W1)
                    val = ib[((size_t)ic * H1 + iy) * W1 + ix];
                v[dy * 4 + dx] = val;
            }
        }
        const float* wp = w + (size_t)ocg * 8192 + ic * 16;   // w[oc][ic][k]
        #pragma unroll
        for (int j = 0; j < 16; ++j) {
            float a = acc[j];
            #pragma unroll
            for (int k = 0; k < 16; ++k) a = fmaf(v[k], wp[j * 512 + k], a);
            acc[j] = a;
        }
    }
    float* ob = out + ((size_t)b * C2 + ocg * 16) * HW2 + (size_t)oy * W2 + ox;
    #pragma unroll
    for (int j = 0; j < 16; ++j) ob[(size_t)j * HW2] = fmaxf(acc[j], 0.f);
}

// ---------------- embedding squared norms ----------------
__global__ void e2_kernel(const float* __restrict__ emb, float* __restrict__ e2) {
    int e = blockIdx.x * 64 + threadIdx.x;            // 512 total
    float s = 0.f;
    #pragma unroll
    for (int c = 0; c < E_DIM; ++c) {
        float v = emb[(size_t)e * E_DIM + c];
        s = fmaf(v, v, s);
    }
    e2[e] = s;
}

// ---- VQ: argmin(|e|^2 - 2 z.e); embeddings via wave-uniform scalar loads ----
__global__ __launch_bounds__(256) void vq_kernel(const float* __restrict__ z,
        const float* __restrict__ emb, const float* __restrict__ e2,
        float* __restrict__ q) {
    int r  = blockIdx.x * 256 + threadIdx.x;          // vector id
    int hw = r & (HW2 - 1);
    int b  = r >> 12;
    const float* zp = z + (size_t)b * C2 * HW2 + hw;
    float zv[64];
    #pragma unroll
    for (int c = 0; c < 64; ++c) zv[c] = zp[(size_t)c * HW2];   // coalesced per c

    float best = 3.4e38f;
    int bi = 0;
    #pragma unroll 2
    for (int e = 0; e < N_EMB; ++e) {
        const float* ep = emb + (size_t)e * E_DIM;    // uniform -> s_load
        float d0 = 0.f, d1 = 0.f, d2 = 0.f, d3 = 0.f;
        #pragma unroll
        for (int k = 0; k < 16; ++k) {
            d0 = fmaf(zv[4 * k + 0], ep[4 * k + 0], d0);
            d1 = fmaf(zv[4 * k + 1], ep[4 * k + 1], d1);
            d2 = fmaf(zv[4 * k + 2], ep[4 * k + 2], d2);
            d3 = fmaf(zv[4 * k + 3], ep[4 * k + 3], d3);
        }
        float score = e2[e] - 2.f * ((d0 + d1) + (d2 + d3));
        if (score < best) { best = score; bi = e; }
    }
    // gather chosen embedding -> q (q is only 4B-aligned: scalar stores)
    const float4* er = (const float4*)(emb + (size_t)bi * E_DIM);
    float* qp = q + (size_t)r * E_DIM;
    #pragma unroll
    for (int k = 0; k < 16; ++k) {
        float4 ev = er[k];
        qp[4 * k + 0] = ev.x;
        qp[4 * k + 1] = ev.y;
        qp[4 * k + 2] = ev.z;
        qp[4 * k + 3] = ev.w;
    }
}

// ---------------- loss = 1.25 * mean((q_flat - z_flat)^2) ----------------
__global__ __launch_bounds__(256) void loss_partial(const float* __restrict__ q,
        const float* __restrict__ z, float* __restrict__ part, int n) {
    float s = 0.f;
    int stride = gridDim.x * 256;
    for (int i = blockIdx.x * 256 + threadIdx.x; i < n; i += stride) {
        float d = q[i] - z[i];
        s = fmaf(d, d, s);
    }
    #pragma unroll
    for (int off = 32; off; off >>= 1) s += __shfl_down(s, off, 64);
    __shared__ float red[4];
    int lane = threadIdx.x & 63, wid = threadIdx.x >> 6;
    if (lane == 0) red[wid] = s;
    __syncthreads();
    if (threadIdx.x == 0) part[blockIdx.x] = (red[0] + red[1]) + (red[2] + red[3]);
}

__global__ __launch_bounds__(256) void loss_final(const float* __restrict__ part,
        float* __restrict__ loss, float scale) {
    float s = 0.f;
    for (int i = threadIdx.x; i < 2048; i += 256) s += part[i];
    #pragma unroll
    for (int off = 32; off; off >>= 1) s += __shfl_down(s, off, 64);
    __shared__ float red[4];
    int lane = threadIdx.x & 63, wid = threadIdx.x >> 6;
    if (lane == 0) red[wid] = s;
    __syncthreads();
    if (threadIdx.x == 0)
        *loss = ((red[0] + red[1]) + (red[2] + red[3])) * scale;
}

// ---- transpose ConvTranspose weights: (CI,CO,4,4) -> [cls][ic][tap][oc] ----
template<int CI, int CO>
__global__ void transpose_deconv_w(const float* __restrict__ w, float* __restrict__ wt) {
    int i = blockIdx.x * 256 + threadIdx.x;
    if (i >= 4 * CI * 4 * CO) return;
    int oc  = i % CO;
    int tap = (i / CO) % 4;
    int ic  = (i / (CO * 4)) % CI;
    int cls = i / (CO * 4 * CI);
    int py = cls >> 1, px = cls & 1, ty = tap >> 1, tx = tap & 1;
    int ky = py ? (ty ? 0 : 2) : (ty ? 3 : 1);
    int kx = px ? (tx ? 0 : 2) : (tx ? 3 : 1);
    wt[i] = w[(((size_t)ic * CO + oc) * 4 + ky) * 4 + kx];
}

// ---- ConvTranspose k4 s2 p1 as 4 parity-class 2x2 convs, ReLU ----
// oc split into NOCG groups of 16 per thread
template<int CI, int CO, int NOCG, int HI, int WI>
__global__ __launch_bounds__(256) void deconv_kernel(const float* __restrict__ in,
        const float* __restrict__ wt, const float* __restrict__ bias,
        float* __restrict__ out) {
    constexpr int COP = CO / NOCG;   // 16
    int cls = blockIdx.y;
    int py = cls >> 1, px = cls & 1;
    int t = blockIdx.x * 256 + threadIdx.x;           // G*HI*WI*NOCG threads
    int x   = t & (WI - 1);
    int y   = (t / WI) & (HI - 1);
    int ocg = (t / (WI * HI)) % NOCG;
    int b   = t / (WI * HI * NOCG);
    int iy1 = y + (py ? 1 : -1);
    int ix1 = x + (px ? 1 : -1);
    bool vy1 = (unsigned)iy1 < HI, vx1 = (unsigned)ix1 < WI;
    float acc[COP];
    #pragma unroll
    for (int j = 0; j < COP; ++j) acc[j] = bias[ocg * COP + j];
    const float* ib = in + (size_t)b * CI * HI * WI;
    for (int ic = 0; ic < CI; ++ic) {
        const float* p = ib + (size_t)ic * HI * WI;
        float v0 = p[y * WI + x];
        float v1 = vx1 ? p[y * WI + ix1] : 0.f;
        float v2 = vy1 ? p[iy1 * WI + x] : 0.f;
        float v3 = (vy1 && vx1) ? p[iy1 * WI + ix1] : 0.f;
        const float* wp = wt + (((size_t)cls * CI + ic) * 4) * CO + ocg * COP;
        #pragma unroll
        for (int j = 0; j < COP; ++j) {
            float a = acc[j];
            a = fmaf(v0, wp[j], a);
            a = fmaf(v1, wp[CO + j], a);
            a = fmaf(v2, wp[2 * CO + j], a);
            a = fmaf(v3, wp[3 * CO + j], a);
            acc[j] = a;
        }
    }
    int oy = 2 * y + py, ox = 2 * x + px;
    float* ob = out + ((size_t)b * CO + ocg * COP) * (4 * HI * WI)
                    + (size_t)oy * (2 * WI) + ox;
    #pragma unroll
    for (int j = 0; j < COP; ++j)
        ob[(size_t)j * (4 * HI * WI)] = fmaxf(acc[j], 0.f);
}

// ---------------- conv3: 32->3, k3 s1 p1, sigmoid ----------------
__global__ __launch_bounds__(256) void conv3_kernel(const float* __restrict__ in,
        const float* __restrict__ w, const float* __restrict__ bias,
        float* __restrict__ out) {
    int t = blockIdx.x * 256 + threadIdx.x;           // G*256*256 threads
    int ox = t & (W0 - 1);
    int oy = (t >> 8) & (H0 - 1);
    int b  = t >> 16;
    float a0 = bias[0], a1 = bias[1], a2 = bias[2];
    const float* ib = in + (size_t)b * (32 * H0 * W0);
    for (int ic = 0; ic < 32; ++ic) {
        const float* p = ib + (size_t)ic * (H0 * W0);
        float v[9];
        #pragma unroll
        for (int dy = 0; dy < 3; ++dy) {
            int iy = oy - 1 + dy;
            #pragma unroll
            for (int dx = 0; dx < 3; ++dx) {
                int ix = ox - 1 + dx;
                v[dy * 3 + dx] = ((unsigned)iy < H0 && (unsigned)ix < W0)
                                 ? p[(size_t)iy * W0 + ix] : 0.f;
            }
        }
        #pragma unroll
        for (int k = 0; k < 9; ++k) {
            a0 = fmaf(v[k], w[(0 * 32 + ic) * 9 + k], a0);
            a1 = fmaf(v[k], w[(1 * 32 + ic) * 9 + k], a1);
            a2 = fmaf(v[k], w[(2 * 32 + ic) * 9 + k], a2);
        }
    }
    float* ob = out + (size_t)b * (3 * H0 * W0) + (size_t)oy * W0 + ox;
    ob[0]                      = 1.f / (1.f + expf(-a0));
    ob[(size_t)1 * H0 * W0]    = 1.f / (1.f + expf(-a1));
    ob[(size_t)2 * H0 * W0]    = 1.f / (1.f + expf(-a2));
}

// ---------------- launch ----------------
extern "C" void kernel_launch(void* const* d_in, const int* in_sizes, int n_in,
                              void* d_out, int out_size, void* d_ws, size_t ws_size,
                              hipStream_t stream) {
    (void)in_sizes; (void)n_in; (void)out_size;
    const float* x   = (const float*)d_in[0];
    const float* e1w = (const float*)d_in[1];
    const float* e1b = (const float*)d_in[2];
    const float* e2w = (const float*)d_in[3];
    const float* e2b = (const float*)d_in[4];
    const float* emb = (const float*)d_in[5];
    const float* d1w = (const float*)d_in[6];
    const float* d1b = (const float*)d_in[7];
    const float* d2w = (const float*)d_in[8];
    const float* d2b = (const float*)d_in[9];
    const float* d3w = (const float*)d_in[10];
    const float* d3b = (const float*)d_in[11];

    float* out   = (float*)d_out;
    float* recon = out;                    // 6291456 floats
    float* loss  = out + 6291456;          // 1 float
    float* q     = out + 6291457;          // 8388608 floats (only 4B-aligned!)

    // ---- workspace layout (floats) ----
    float* ws  = (float*)d_ws;
    float* wt1 = ws;                       // 65536
    float* wt2 = ws + 65536;               // 32768
    float* e2v = ws + 98304;               // 512
    float* prt = ws + 98816;               // 2048 (always fully written: 2048 partials)
    float* big = ws + 100864;              // shared big region

    size_t wsf  = ws_size / sizeof(float);
    size_t bigf = (wsf > 100864) ? wsf - 100864 : 0;
    int G = 32;
    while (G > 1 && (size_t)G * 3145728 > bigf) G >>= 1;  // decoder peak: G*(h1+h2)
    int ngrp = BB / G;
    bool encFull = (bigf >= 25165824);     // z1(16M) + z(8.4M) floats

    transpose_deconv_w<64, 64><<<256, 256, 0, stream>>>(d1w, wt1);
    transpose_deconv_w<64, 32><<<128, 256, 0, stream>>>(d2w, wt2);
    e2_kernel<<<8, 64, 0, stream>>>(emb, e2v);

    float* zfull = big + 16777216;
    if (encFull) {
        // full-batch encoder: z1 = big[0..16M), z = big[16M..25.2M)
        conv1_kernel<<<4096, 256, 0, stream>>>(x, e1w, e1b, big);
        conv2_kernel<<<2048, 256, 0, stream>>>(big, e2w, e2b, zfull);
        vq_kernel<<<512, 256, 0, stream>>>(zfull, emb, e2v, q);
        loss_partial<<<2048, 256, 0, stream>>>(q, zfull, prt, NZ);
    } else {
        for (int g = 0; g < ngrp; ++g) {
            const float* xg = x + (size_t)g * G * (C_IN * H0 * W0);
            float* z1g = big;                              // G*524288
            float* zg  = big + (size_t)G * 524288;         // G*262144
            float* qg  = q + (size_t)g * G * 262144;
            conv1_kernel<<<128 * G, 256, 0, stream>>>(xg, e1w, e1b, z1g);
            conv2_kernel<<<64 * G, 256, 0, stream>>>(z1g, e2w, e2b, zg);
            vq_kernel<<<16 * G, 256, 0, stream>>>(zg, emb, e2v, qg);
            loss_partial<<<64 * G, 256, 0, stream>>>(qg, zg, prt + g * 64 * G,
                                                     G * 262144);
        }
    }

    // decoder (grouped; reuses big region — encoder data consumed by now)
    for (int g = 0; g < ngrp; ++g) {
        float* qg  = q + (size_t)g * G * 262144;
        float* h1g = big;                              // G*1048576
        float* h2g = big + (size_t)G * 1048576;        // G*2097152
        deconv_kernel<64, 64, 4, 64, 64>
            <<<dim3(64 * G, 4), 256, 0, stream>>>(qg, wt1, d1b, h1g);
        deconv_kernel<64, 32, 2, 128, 128>
            <<<dim3(128 * G, 4), 256, 0, stream>>>(h1g, wt2, d2b, h2g);
        conv3_kernel<<<256 * G, 256, 0, stream>>>(h2g, d3w, d3b,
                                                  recon + (size_t)g * G * 196608);
    }
    loss_final<<<1, 256, 0, stream>>>(prt, loss, 1.25f / (float)NZ);
}

// Round 4
// 1710.528 us; speedup vs baseline: 2.3777x; 2.3777x over previous
//
#include <hip/hip_runtime.h>
#include <math.h>

// ---------------- problem constants ----------------
#define BB    32
#define C_IN  3
#define H0    256
#define W0    256
#define C1    32          // conv1 out: (B,32,128,128)
#define H1    128
#define W1    128
#define C2    64          // conv2 out: (B,64,64,64)
#define H2    64
#define W2    64
#define HW2   (H2*W2)     // 4096
#define N_EMB 512
#define E_DIM 64
#define NZ    (BB*C2*HW2) // 8388608

// ---- conv1: 3->32, k4 s2 p1, ReLU. 1 thread = 1 pixel, all 32 oc.
// Weights wave-uniform -> s_load.
__global__ __launch_bounds__(256, 4) void conv1_kernel(const float* __restrict__ x,
        const float* __restrict__ w, const float* __restrict__ bias,
        float* __restrict__ out) {
    int t = blockIdx.x * 256 + threadIdx.x;           // G*128*128 threads
    int ox = t & (W1 - 1);
    int oy = (t >> 7) & (H1 - 1);
    int b  = t >> 14;
    const float* xb = x + (size_t)b * (C_IN * H0 * W0);
    float v[48];
    #pragma unroll
    for (int ic = 0; ic < 3; ++ic)
        #pragma unroll
        for (int dy = 0; dy < 4; ++dy) {
            int iy = oy * 2 - 1 + dy;
            #pragma unroll
            for (int dx = 0; dx < 4; ++dx) {
                int ix = ox * 2 - 1 + dx;
                float val = 0.f;
                if ((unsigned)iy < H0 && (unsigned)ix < W0)
                    val = xb[((size_t)ic * H0 + iy) * W0 + ix];
                v[(ic * 4 + dy) * 4 + dx] = val;
            }
        }
    float* ob = out + (size_t)b * (C1 * H1 * W1) + (size_t)oy * W1 + ox;
    #pragma unroll
    for (int oc = 0; oc < C1; ++oc) {
        float a = bias[oc];
        #pragma unroll
        for (int k = 0; k < 48; ++k) a = fmaf(v[k], w[oc * 48 + k], a);
        ob[(size_t)oc * (H1 * W1)] = fmaxf(a, 0.f);
    }
}

// ---- conv2: 32->64, k4 s2 p1, ReLU. 1 thread = 1 pixel, all 64 oc.
// acc[64] fits under the 128-VGPR cap from launch_bounds(256,4): no spill.
__global__ __launch_bounds__(256, 4) void conv2_kernel(const float* __restrict__ in,
        const float* __restrict__ w, const float* __restrict__ bias,
        float* __restrict__ out) {
    int t = blockIdx.x * 256 + threadIdx.x;           // G*64*64 threads
    int ox = t & (W2 - 1);
    int oy = (t >> 6) & (H2 - 1);
    int b  = t >> 12;
    float acc[64];
    #pragma unroll
    for (int oc = 0; oc < 64; ++oc) acc[oc] = bias[oc];
    const float* ib = in + (size_t)b * (C1 * H1 * W1);
    for (int ic = 0; ic < 32; ++ic) {
        float v[16];
        #pragma unroll
        for (int dy = 0; dy < 4; ++dy) {
            int iy = oy * 2 - 1 + dy;
            #pragma unroll
            for (int dx = 0; dx < 4; ++dx) {
                int ix = ox * 2 - 1 + dx;
                float val = 0.f;
                if ((unsigned)iy < H1 && (unsigned)ix < W1)
                    val = ib[((size_t)ic * H1 + iy) * W1 + ix];
                v[dy * 4 + dx] = val;
            }
        }
        #pragma unroll
        for (int oc = 0; oc < 64; ++oc) {
            const float* wp = w + ((size_t)oc * 32 + ic) * 16;  // uniform -> s_load
            float a = acc[oc];
            #pragma unroll
            for (int k = 0; k < 16; ++k) a = fmaf(v[k], wp[k], a);
            acc[oc] = a;
        }
    }
    float* ob = out + (size_t)b * (C2 * HW2) + (size_t)oy * W2 + ox;
    #pragma unroll
    for (int oc = 0; oc < 64; ++oc) ob[(size_t)oc * HW2] = fmaxf(acc[oc], 0.f);
}

// ---------------- embedding squared norms ----------------
__global__ void e2_kernel(const float* __restrict__ emb, float* __restrict__ e2) {
    int e = blockIdx.x * 64 + threadIdx.x;            // 512 total
    float s = 0.f;
    #pragma unroll
    for (int c = 0; c < E_DIM; ++c) {
        float v = emb[(size_t)e * E_DIM + c];
        s = fmaf(v, v, s);
    }
    e2[e] = s;
}

// ---- VQ: argmin(|e|^2 - 2 z.e); embeddings via wave-uniform scalar loads ----
__global__ __launch_bounds__(256, 4) void vq_kernel(const float* __restrict__ z,
        const float* __restrict__ emb, const float* __restrict__ e2,
        float* __restrict__ q) {
    int r  = blockIdx.x * 256 + threadIdx.x;          // vector id
    int hw = r & (HW2 - 1);
    int b  = r >> 12;
    const float* zp = z + (size_t)b * C2 * HW2 + hw;
    float zv[64];
    #pragma unroll
    for (int c = 0; c < 64; ++c) zv[c] = zp[(size_t)c * HW2];   // coalesced per c

    float best = 3.4e38f;
    int bi = 0;
    #pragma unroll 2
    for (int e = 0; e < N_EMB; ++e) {
        const float* ep = emb + (size_t)e * E_DIM;    // uniform -> s_load
        float d0 = 0.f, d1 = 0.f, d2 = 0.f, d3 = 0.f;
        #pragma unroll
        for (int k = 0; k < 16; ++k) {
            d0 = fmaf(zv[4 * k + 0], ep[4 * k + 0], d0);
            d1 = fmaf(zv[4 * k + 1], ep[4 * k + 1], d1);
            d2 = fmaf(zv[4 * k + 2], ep[4 * k + 2], d2);
            d3 = fmaf(zv[4 * k + 3], ep[4 * k + 3], d3);
        }
        float score = e2[e] - 2.f * ((d0 + d1) + (d2 + d3));
        if (score < best) { best = score; bi = e; }
    }
    // gather chosen embedding -> q (q is only 4B-aligned: scalar stores)
    const float4* er = (const float4*)(emb + (size_t)bi * E_DIM);
    float* qp = q + (size_t)r * E_DIM;
    #pragma unroll
    for (int k = 0; k < 16; ++k) {
        float4 ev = er[k];
        qp[4 * k + 0] = ev.x;
        qp[4 * k + 1] = ev.y;
        qp[4 * k + 2] = ev.z;
        qp[4 * k + 3] = ev.w;
    }
}

// ---------------- loss = 1.25 * mean((q_flat - z_flat)^2) ----------------
__global__ __launch_bounds__(256) void loss_partial(const float* __restrict__ q,
        const float* __restrict__ z, float* __restrict__ part, int n) {
    float s = 0.f;
    int stride = gridDim.x * 256;
    for (int i = blockIdx.x * 256 + threadIdx.x; i < n; i += stride) {
        float d = q[i] - z[i];
        s = fmaf(d, d, s);
    }
    #pragma unroll
    for (int off = 32; off; off >>= 1) s += __shfl_down(s, off, 64);
    __shared__ float red[4];
    int lane = threadIdx.x & 63, wid = threadIdx.x >> 6;
    if (lane == 0) red[wid] = s;
    __syncthreads();
    if (threadIdx.x == 0) part[blockIdx.x] = (red[0] + red[1]) + (red[2] + red[3]);
}

__global__ __launch_bounds__(256) void loss_final(const float* __restrict__ part,
        float* __restrict__ loss, float scale) {
    float s = 0.f;
    for (int i = threadIdx.x; i < 2048; i += 256) s += part[i];
    #pragma unroll
    for (int off = 32; off; off >>= 1) s += __shfl_down(s, off, 64);
    __shared__ float red[4];
    int lane = threadIdx.x & 63, wid = threadIdx.x >> 6;
    if (lane == 0) red[wid] = s;
    __syncthreads();
    if (threadIdx.x == 0)
        *loss = ((red[0] + red[1]) + (red[2] + red[3])) * scale;
}

// ---- transpose ConvTranspose weights: (CI,CO,4,4) -> [cls][ic][tap][oc] ----
template<int CI, int CO>
__global__ void transpose_deconv_w(const float* __restrict__ w, float* __restrict__ wt) {
    int i = blockIdx.x * 256 + threadIdx.x;
    if (i >= 4 * CI * 4 * CO) return;
    int oc  = i % CO;
    int tap = (i / CO) % 4;
    int ic  = (i / (CO * 4)) % CI;
    int cls = i / (CO * 4 * CI);
    int py = cls >> 1, px = cls & 1, ty = tap >> 1, tx = tap & 1;
    int ky = py ? (ty ? 0 : 2) : (ty ? 3 : 1);
    int kx = px ? (tx ? 0 : 2) : (tx ? 3 : 1);
    wt[i] = w[(((size_t)ic * CO + oc) * 4 + ky) * 4 + kx];
}

// ---- ConvTranspose k4 s2 p1 as 4 parity-class 2x2 convs, ReLU ----
// 1 thread = 1 input pixel, ALL CO outputs; weights wave-uniform -> s_load.
template<int CI, int CO, int HI, int WI>
__global__ __launch_bounds__(256, 4) void deconv_kernel(const float* __restrict__ in,
        const float* __restrict__ wt, const float* __restrict__ bias,
        float* __restrict__ out) {
    int cls = blockIdx.y;
    int py = cls >> 1, px = cls & 1;
    int t = blockIdx.x * 256 + threadIdx.x;           // G*HI*WI threads
    int x = t & (WI - 1);
    int y = (t / WI) & (HI - 1);
    int b = t / (WI * HI);
    int iy1 = y + (py ? 1 : -1);
    int ix1 = x + (px ? 1 : -1);
    bool vy1 = (unsigned)iy1 < HI, vx1 = (unsigned)ix1 < WI;
    float acc[CO];
    #pragma unroll
    for (int oc = 0; oc < CO; ++oc) acc[oc] = bias[oc];
    const float* ib = in + (size_t)b * CI * HI * WI;
    for (int ic = 0; ic < CI; ++ic) {
        const float* p = ib + (size_t)ic * HI * WI;
        float v0 = p[y * WI + x];
        float v1 = vx1 ? p[y * WI + ix1] : 0.f;
        float v2 = vy1 ? p[iy1 * WI + x] : 0.f;
        float v3 = (vy1 && vx1) ? p[iy1 * WI + ix1] : 0.f;
        const float* wp = wt + (((size_t)cls * CI + ic) * 4) * CO;   // uniform
        #pragma unroll
        for (int oc = 0; oc < CO; ++oc) {
            float a = acc[oc];
            a = fmaf(v0, wp[oc], a);
            a = fmaf(v1, wp[CO + oc], a);
            a = fmaf(v2, wp[2 * CO + oc], a);
            a = fmaf(v3, wp[3 * CO + oc], a);
            acc[oc] = a;
        }
    }
    int oy = 2 * y + py, ox = 2 * x + px;
    float* ob = out + (size_t)b * CO * (4 * HI * WI) + (size_t)oy * (2 * WI) + ox;
    #pragma unroll
    for (int oc = 0; oc < CO; ++oc)
        ob[(size_t)oc * (4 * HI * WI)] = fmaxf(acc[oc], 0.f);
}

// ---- conv3: 32->3, k3 s1 p1, sigmoid. 1 thread = 4 consecutive x pixels. ----
__global__ __launch_bounds__(256, 4) void conv3_kernel(const float* __restrict__ in,
        const float* __restrict__ w, const float* __restrict__ bias,
        float* __restrict__ out) {
    int t = blockIdx.x * 256 + threadIdx.x;           // G*256*256/4 threads
    int gx = t & 63;                                  // 64 groups of 4 px per row
    int oy = (t >> 6) & (H0 - 1);
    int b  = t >> 14;
    int ox0 = gx * 4;
    float a[3][4];
    #pragma unroll
    for (int oc = 0; oc < 3; ++oc)
        #pragma unroll
        for (int p = 0; p < 4; ++p) a[oc][p] = bias[oc];
    const float* ib = in + (size_t)b * (32 * H0 * W0);
    for (int ic = 0; ic < 32; ++ic) {
        const float* p = ib + (size_t)ic * (H0 * W0);
        float v[3][6];
        #pragma unroll
        for (int dy = 0; dy < 3; ++dy) {
            int iy = oy - 1 + dy;
            bool ry = (unsigned)iy < H0;
            #pragma unroll
            for (int j = 0; j < 6; ++j) {
                int ix = ox0 - 1 + j;
                v[dy][j] = (ry && (unsigned)ix < W0) ? p[(size_t)iy * W0 + ix] : 0.f;
            }
        }
        #pragma unroll
        for (int dy = 0; dy < 3; ++dy)
            #pragma unroll
            for (int dx = 0; dx < 3; ++dx) {
                int k = dy * 3 + dx;
                float w0 = w[(0 * 32 + ic) * 9 + k];   // uniform -> s_load
                float w1 = w[(1 * 32 + ic) * 9 + k];
                float w2 = w[(2 * 32 + ic) * 9 + k];
                #pragma unroll
                for (int px = 0; px < 4; ++px) {
                    float val = v[dy][px + dx];
                    a[0][px] = fmaf(val, w0, a[0][px]);
                    a[1][px] = fmaf(val, w1, a[1][px]);
                    a[2][px] = fmaf(val, w2, a[2][px]);
                }
            }
    }
    float* ob = out + (size_t)b * (3 * H0 * W0) + (size_t)oy * W0 + ox0;
    #pragma unroll
    for (int oc = 0; oc < 3; ++oc) {
        float4 r;
        r.x = 1.f / (1.f + expf(-a[oc][0]));
        r.y = 1.f / (1.f + expf(-a[oc][1]));
        r.z = 1.f / (1.f + expf(-a[oc][2]));
        r.w = 1.f / (1.f + expf(-a[oc][3]));
        *(float4*)(ob + (size_t)oc * (H0 * W0)) = r;
    }
}

// ---------------- launch ----------------
extern "C" void kernel_launch(void* const* d_in, const int* in_sizes, int n_in,
                              void* d_out, int out_size, void* d_ws, size_t ws_size,
                              hipStream_t stream) {
    (void)in_sizes; (void)n_in; (void)out_size;
    const float* x   = (const float*)d_in[0];
    const float* e1w = (const float*)d_in[1];
    const float* e1b = (const float*)d_in[2];
    const float* e2w = (const float*)d_in[3];
    const float* e2b = (const float*)d_in[4];
    const float* emb = (const float*)d_in[5];
    const float* d1w = (const float*)d_in[6];
    const float* d1b = (const float*)d_in[7];
    const float* d2w = (const float*)d_in[8];
    const float* d2b = (const float*)d_in[9];
    const float* d3w = (const float*)d_in[10];
    const float* d3b = (const float*)d_in[11];

    float* out   = (float*)d_out;
    float* recon = out;                    // 6291456 floats
    float* loss  = out + 6291456;          // 1 float
    float* q     = out + 6291457;          // 8388608 floats (only 4B-aligned!)

    // ---- workspace layout (floats) ----
    float* ws  = (float*)d_ws;
    float* wt1 = ws;                       // 65536
    float* wt2 = ws + 65536;               // 32768
    float* e2v = ws + 98304;               // 512
    float* prt = ws + 98816;               // 2048 partials (always fully written)
    float* big = ws + 100864;              // shared big region

    size_t wsf  = ws_size / sizeof(float);
    size_t bigf = (wsf > 100864) ? wsf - 100864 : 0;
    int G = 32;
    while (G > 1 && (size_t)G * 3145728 > bigf) G >>= 1;  // decoder peak: G*(h1+h2)
    int ngrp = BB / G;
    bool encFull = (bigf >= 25165824);     // z1(16.8M) + z(8.4M) floats

    transpose_deconv_w<64, 64><<<256, 256, 0, stream>>>(d1w, wt1);
    transpose_deconv_w<64, 32><<<128, 256, 0, stream>>>(d2w, wt2);
    e2_kernel<<<8, 64, 0, stream>>>(emb, e2v);

    float* zfull = big + 16777216;
    if (encFull) {
        conv1_kernel<<<2048, 256, 0, stream>>>(x, e1w, e1b, big);
        conv2_kernel<<<512, 256, 0, stream>>>(big, e2w, e2b, zfull);
        vq_kernel<<<512, 256, 0, stream>>>(zfull, emb, e2v, q);
        loss_partial<<<2048, 256, 0, stream>>>(q, zfull, prt, NZ);
    } else {
        for (int g = 0; g < ngrp; ++g) {
            const float* xg = x + (size_t)g * G * (C_IN * H0 * W0);
            float* z1g = big;                              // G*524288
            float* zg  = big + (size_t)G * 524288;         // G*262144
            float* qg  = q + (size_t)g * G * 262144;
            conv1_kernel<<<64 * G, 256, 0, stream>>>(xg, e1w, e1b, z1g);
            conv2_kernel<<<16 * G, 256, 0, stream>>>(z1g, e2w, e2b, zg);
            vq_kernel<<<16 * G, 256, 0, stream>>>(zg, emb, e2v, qg);
            loss_partial<<<64 * G, 256, 0, stream>>>(qg, zg, prt + g * 64 * G,
                                                     G * 262144);
        }
    }

    // decoder (grouped; reuses big region — encoder data consumed by now)
    for (int g = 0; g < ngrp; ++g) {
        float* qg  = q + (size_t)g * G * 262144;
        float* h1g = big;                              // G*1048576
        float* h2g = big + (size_t)G * 1048576;        // G*2097152
        deconv_kernel<64, 64, 64, 64>
            <<<dim3(16 * G, 4), 256, 0, stream>>>(qg, wt1, d1b, h1g);
        deconv_kernel<64, 32, 128, 128>
            <<<dim3(64 * G, 4), 256, 0, stream>>>(h1g, wt2, d2b, h2g);
        conv3_kernel<<<64 * G, 256, 0, stream>>>(h2g, d3w, d3b,
                                                 recon + (size_t)g * G * 196608);
    }
    loss_final<<<1, 256, 0, stream>>>(prt, loss, 1.25f / (float)NZ);
}

// Round 5
// 1308.515 us; speedup vs baseline: 3.1082x; 1.3072x over previous
//
#include <hip/hip_runtime.h>
#include <math.h>

// ---------------- problem constants ----------------
#define BB    32
#define C_IN  3
#define H0    256
#define W0    256
#define C1    32
#define H1    128
#define W1    128
#define C2    64
#define H2    64
#define W2    64
#define HW2   (H2*W2)     // 4096
#define N_EMB 512
#define E_DIM 64
#define NZ    (BB*C2*HW2) // 8388608

typedef unsigned short u16;
typedef unsigned int   uint;
typedef __attribute__((ext_vector_type(8))) short short8;
typedef __attribute__((ext_vector_type(4))) float f32x4;

__device__ inline u16 f2bf(float f) {
    uint u = __builtin_bit_cast(uint, f);
    u += 0x7FFF + ((u >> 16) & 1);          // RNE
    return (u16)(u >> 16);
}
__device__ inline float bf2f(u16 h) {
    uint u = (uint)h << 16;
    return __builtin_bit_cast(float, u);
}
__device__ inline f32x4 mfma16(short8 a, short8 b, f32x4 c) {
    return __builtin_amdgcn_mfma_f32_16x16x32_bf16(a, b, c, 0, 0, 0);
}

// ---- zero the halo border of an NHWC padded buffer (interior at (1,1)) ----
template<int C, int HP, int WP, int H, int W>
__global__ __launch_bounds__(256) void border_zero(u16* buf, int nimg) {
    int t = blockIdx.x * 256 + threadIdx.x;
    if (t >= nimg * HP * WP) return;
    int x = t % WP, y = (t / WP) % HP;
    if (y >= 1 && y < 1 + H && x >= 1 && x < 1 + W) return;
    uint4 z4; z4.x = 0; z4.y = 0; z4.z = 0; z4.w = 0;
    uint4* p = (uint4*)(buf + (size_t)t * C);
    #pragma unroll
    for (int i = 0; i < C / 8; ++i) p[i] = z4;
}

// ---- weight prep: deconv (CI,CO,4,4) fp32 -> bf16 [cls][oc][t*CI+ic] ----
template<int CI, int CO>
__global__ __launch_bounds__(256) void wt_deconv(const float* __restrict__ w,
        u16* __restrict__ wb) {
    int i = blockIdx.x * 256 + threadIdx.x;
    if (i >= 4 * CO * 4 * CI) return;
    int ic  = i % CI;
    int t   = (i / CI) & 3;
    int oc  = (i / (CI * 4)) % CO;
    int cls = i / (CI * 4 * CO);
    int py = cls >> 1, px = cls & 1, ty = t >> 1, tx = t & 1;
    int ky = py ? (ty ? 0 : 2) : (ty ? 3 : 1);
    int kx = px ? (tx ? 0 : 2) : (tx ? 3 : 1);
    wb[i] = f2bf(w[(((size_t)ic * CO + oc) * 4 + ky) * 4 + kx]);
}

// ---- weight prep: conv2 (64,32,4,4) fp32 -> bf16 [oc][tap*32+ic] ----
__global__ __launch_bounds__(256) void wt_conv2(const float* __restrict__ w,
        u16* __restrict__ wb) {
    int i = blockIdx.x * 256 + threadIdx.x;
    if (i >= 64 * 512) return;
    int ic = i & 31;
    int k  = (i >> 5) & 15;
    int oc = i >> 9;
    wb[i] = f2bf(w[(size_t)(oc * 32 + ic) * 16 + k]);
}

// ---- conv1: 3->32, k4 s2 p1, ReLU; out = NHWC bf16 padded (131x131) ----
__global__ __launch_bounds__(256) void conv1_kernel(const float* __restrict__ x,
        const float* __restrict__ w, const float* __restrict__ bias,
        u16* __restrict__ out) {
    int t = blockIdx.x * 256 + threadIdx.x;           // 32*128*128
    int ox = t & (W1 - 1);
    int oy = (t >> 7) & (H1 - 1);
    int b  = t >> 14;
    const float* xb = x + (size_t)b * (C_IN * H0 * W0);
    float v[48];
    #pragma unroll
    for (int ic = 0; ic < 3; ++ic)
        #pragma unroll
        for (int dy = 0; dy < 4; ++dy) {
            int iy = oy * 2 - 1 + dy;
            #pragma unroll
            for (int dx = 0; dx < 4; ++dx) {
                int ix = ox * 2 - 1 + dx;
                float val = 0.f;
                if ((unsigned)iy < H0 && (unsigned)ix < W0)
                    val = xb[((size_t)ic * H0 + iy) * W0 + ix];
                v[(ic * 4 + dy) * 4 + dx] = val;
            }
        }
    u16 h[32];
    #pragma unroll
    for (int oc = 0; oc < C1; ++oc) {
        float a = bias[oc];
        #pragma unroll
        for (int k = 0; k < 48; ++k) a = fmaf(v[k], w[oc * 48 + k], a);
        h[oc] = f2bf(fmaxf(a, 0.f));
    }
    uint4* dst = (uint4*)(out + ((size_t)(b * 131 + oy + 1) * 131 + ox + 1) * 32);
    #pragma unroll
    for (int i = 0; i < 4; ++i) {
        uint4 u;
        u.x = (uint)h[i*8+0] | ((uint)h[i*8+1] << 16);
        u.y = (uint)h[i*8+2] | ((uint)h[i*8+3] << 16);
        u.z = (uint)h[i*8+4] | ((uint)h[i*8+5] << 16);
        u.w = (uint)h[i*8+6] | ((uint)h[i*8+7] << 16);
        dst[i] = u;
    }
}

// ---- conv2 via MFMA: 32->64 k4 s2; in z1p NHWC bf16 padded; out z NHWC fp32 ----
__global__ __launch_bounds__(256) void conv2_mfma(const u16* __restrict__ z1p,
        const u16* __restrict__ wb, const float* __restrict__ bias,
        float* __restrict__ z) {
    int wid = threadIdx.x >> 6, lane = threadIdx.x & 63;
    int m0 = blockIdx.x * 128 + wid * 32;             // 32 pixels per wave
    int b  = m0 >> 12;
    int y  = (m0 >> 6) & 63;
    int x0 = m0 & 63;
    int l15 = lane & 15, lk = lane >> 4;
    f32x4 acc[2][4] = {};
    int xA = x0 + l15, xB = x0 + 16 + l15;
    for (int ks = 0; ks < 16; ++ks) {
        int dy = ks >> 2, dx = ks & 3;
        int rb = (b * 131 + 2 * y + dy) * 131;
        short8 fbA = *(const short8*)(z1p + ((size_t)(rb + 2 * xA + dx)) * 32 + lk * 8);
        short8 fbB = *(const short8*)(z1p + ((size_t)(rb + 2 * xB + dx)) * 32 + lk * 8);
        #pragma unroll
        for (int f = 0; f < 4; ++f) {
            short8 fa = *(const short8*)(wb + (size_t)(f * 16 + l15) * 512 + ks * 32 + lk * 8);
            acc[0][f] = mfma16(fa, fbA, acc[0][f]);
            acc[1][f] = mfma16(fa, fbB, acc[1][f]);
        }
    }
    #pragma unroll
    for (int p = 0; p < 2; ++p) {
        int pix = m0 + p * 16 + l15;
        #pragma unroll
        for (int f = 0; f < 4; ++f) {
            int oc0 = f * 16 + lk * 4;
            float4 bi = *(const float4*)(bias + oc0);
            float4 r;
            r.x = fmaxf(acc[p][f][0] + bi.x, 0.f);
            r.y = fmaxf(acc[p][f][1] + bi.y, 0.f);
            r.z = fmaxf(acc[p][f][2] + bi.z, 0.f);
            r.w = fmaxf(acc[p][f][3] + bi.w, 0.f);
            *(float4*)(z + (size_t)pix * 64 + oc0) = r;
        }
    }
}

// ---------------- embedding squared norms ----------------
__global__ void e2_kernel(const float* __restrict__ emb, float* __restrict__ e2) {
    int e = blockIdx.x * 64 + threadIdx.x;
    float s = 0.f;
    #pragma unroll
    for (int c = 0; c < E_DIM; ++c) {
        float v = emb[(size_t)e * E_DIM + c];
        s = fmaf(v, v, s);
    }
    e2[e] = s;
}

// ---- VQ: z NHWC fp32; argmin(|e|^2 - 2 z.e); scalar q stores (4B-aligned) ----
__global__ __launch_bounds__(256, 4) void vq_kernel(const float* __restrict__ z,
        const float* __restrict__ emb, const float* __restrict__ e2,
        float* __restrict__ q) {
    int r = blockIdx.x * 256 + threadIdx.x;
    float zv[64];
    const float4* zp4 = (const float4*)(z + (size_t)r * 64);
    #pragma unroll
    for (int k = 0; k < 16; ++k) {
        float4 v4 = zp4[k];
        zv[4*k+0] = v4.x; zv[4*k+1] = v4.y; zv[4*k+2] = v4.z; zv[4*k+3] = v4.w;
    }
    float best = 3.4e38f;
    int bi = 0;
    #pragma unroll 2
    for (int e = 0; e < N_EMB; ++e) {
        const float* ep = emb + (size_t)e * E_DIM;    // uniform -> s_load
        float d0 = 0.f, d1 = 0.f, d2 = 0.f, d3 = 0.f;
        #pragma unroll
        for (int k = 0; k < 16; ++k) {
            d0 = fmaf(zv[4*k+0], ep[4*k+0], d0);
            d1 = fmaf(zv[4*k+1], ep[4*k+1], d1);
            d2 = fmaf(zv[4*k+2], ep[4*k+2], d2);
            d3 = fmaf(zv[4*k+3], ep[4*k+3], d3);
        }
        float score = e2[e] - 2.f * ((d0 + d1) + (d2 + d3));
        if (score < best) { best = score; bi = e; }
    }
    const float4* er = (const float4*)(emb + (size_t)bi * E_DIM);
    float* qp = q + (size_t)r * E_DIM;
    #pragma unroll
    for (int k = 0; k < 16; ++k) {
        float4 ev = er[k];
        qp[4*k+0] = ev.x; qp[4*k+1] = ev.y; qp[4*k+2] = ev.z; qp[4*k+3] = ev.w;
    }
}

// ---- loss with faithful NCHW pairing: q_flat[i] vs z_nchw(i); z stored NHWC ----
// block = (b,h): z chunk [w][c] contiguous 4096 floats -> LDS (pad 65)
__global__ __launch_bounds__(256) void loss_tr(const float* __restrict__ q,
        const float* __restrict__ z, float* __restrict__ part) {
    __shared__ float zt[64 * 65];
    int bh = blockIdx.x;                       // b*64 + h
    size_t zbase = (size_t)bh * 4096;
    for (int j = threadIdx.x; j < 4096; j += 256) {
        int w = j >> 6, c = j & 63;
        zt[w * 65 + c] = z[zbase + j];
    }
    __syncthreads();
    int b = bh >> 6, h = bh & 63;
    int w = threadIdx.x & 63;
    float s = 0.f;
    #pragma unroll
    for (int k = 0; k < 16; ++k) {
        int cc = (threadIdx.x >> 6) + k * 4;
        float qv = q[(size_t)b * 262144 + (size_t)cc * 4096 + h * 64 + w];
        float d = qv - zt[w * 65 + cc];
        s = fmaf(d, d, s);
    }
    #pragma unroll
    for (int off = 32; off; off >>= 1) s += __shfl_down(s, off, 64);
    __shared__ float red[4];
    int lane = threadIdx.x & 63, wid = threadIdx.x >> 6;
    if (lane == 0) red[wid] = s;
    __syncthreads();
    if (threadIdx.x == 0) part[blockIdx.x] = (red[0] + red[1]) + (red[2] + red[3]);
}

__global__ __launch_bounds__(256) void loss_final(const float* __restrict__ part,
        float* __restrict__ loss, float scale) {
    float s = 0.f;
    for (int i = threadIdx.x; i < 2048; i += 256) s += part[i];
    #pragma unroll
    for (int off = 32; off; off >>= 1) s += __shfl_down(s, off, 64);
    __shared__ float red[4];
    int lane = threadIdx.x & 63, wid = threadIdx.x >> 6;
    if (lane == 0) red[wid] = s;
    __syncthreads();
    if (threadIdx.x == 0)
        *loss = ((red[0] + red[1]) + (red[2] + red[3])) * scale;
}

// ---- q (NCHW view of q_flat) -> dq NHWC bf16 padded 66x66 ----
__global__ __launch_bounds__(256) void q_transpose(const float* __restrict__ q,
        u16* __restrict__ dq) {
    int t = blockIdx.x * 256 + threadIdx.x;    // 131072
    int x = t & 63, y = (t >> 6) & 63, b = t >> 12;
    const float* src = q + (size_t)b * 262144 + y * 64 + x;
    u16 h[64];
    #pragma unroll
    for (int ic = 0; ic < 64; ++ic) h[ic] = f2bf(src[(size_t)ic * 4096]);
    uint4* dst = (uint4*)(dq + ((size_t)(b * 66 + y + 1) * 66 + x + 1) * 64);
    #pragma unroll
    for (int i = 0; i < 8; ++i) {
        uint4 u;
        u.x = (uint)h[i*8+0] | ((uint)h[i*8+1] << 16);
        u.y = (uint)h[i*8+2] | ((uint)h[i*8+3] << 16);
        u.z = (uint)h[i*8+4] | ((uint)h[i*8+5] << 16);
        u.w = (uint)h[i*8+6] | ((uint)h[i*8+7] << 16);
        dst[i] = u;
    }
}

// ---- deconv k4 s2 p1 via MFMA, 4 parity classes; CI=64; NHWC bf16 padded ----
template<int CO, int HI, int WI>
__global__ __launch_bounds__(256) void deconv_mfma(const u16* __restrict__ in,
        const u16* __restrict__ wb, const float* __restrict__ bias,
        u16* __restrict__ out) {
    constexpr int HPI = HI + 2, WPI = WI + 2;
    constexpr int HPO = 2 * HI + 2, WPO = 2 * WI + 2;
    constexpr int NF = CO / 16;
    int cls = blockIdx.y;
    int py = cls >> 1, px = cls & 1;
    int sy = py ? 1 : -1, sx = px ? 1 : -1;
    int wid = threadIdx.x >> 6, lane = threadIdx.x & 63;
    int m0 = blockIdx.x * 128 + wid * 32;
    int b = m0 / (HI * WI);
    int rem = m0 % (HI * WI);
    int y = rem / WI, x0 = rem % WI;
    int l15 = lane & 15, lk = lane >> 4;
    f32x4 acc[2][NF] = {};
    for (int ks = 0; ks < 8; ++ks) {
        int t = ks >> 1;
        int dy = (t & 2) ? sy : 0;
        int dx = (t & 1) ? sx : 0;
        int rb = (b * HPI + y + dy + 1) * WPI;
        int co = (ks & 1) * 32 + lk * 8;
        short8 fbA = *(const short8*)(in + (size_t)(rb + x0 + l15 + dx + 1) * 64 + co);
        short8 fbB = *(const short8*)(in + (size_t)(rb + x0 + 16 + l15 + dx + 1) * 64 + co);
        #pragma unroll
        for (int f = 0; f < NF; ++f) {
            short8 fa = *(const short8*)(wb + (size_t)(cls * CO + f * 16 + l15) * 256 + ks * 32 + lk * 8);
            acc[0][f] = mfma16(fa, fbA, acc[0][f]);
            acc[1][f] = mfma16(fa, fbB, acc[1][f]);
        }
    }
    int oy = 2 * y + py + 1;
    #pragma unroll
    for (int p = 0; p < 2; ++p) {
        int ox = 2 * (x0 + p * 16 + l15) + px + 1;
        size_t po = ((size_t)(b * HPO + oy) * WPO + ox) * CO;
        #pragma unroll
        for (int f = 0; f < NF; ++f) {
            int oc0 = f * 16 + lk * 4;
            float4 bi = *(const float4*)(bias + oc0);
            float r0 = fmaxf(acc[p][f][0] + bi.x, 0.f);
            float r1 = fmaxf(acc[p][f][1] + bi.y, 0.f);
            float r2 = fmaxf(acc[p][f][2] + bi.z, 0.f);
            float r3 = fmaxf(acc[p][f][3] + bi.w, 0.f);
            uint2 uu;
            uu.x = (uint)f2bf(r0) | ((uint)f2bf(r1) << 16);
            uu.y = (uint)f2bf(r2) | ((uint)f2bf(r3) << 16);
            *(uint2*)(out + po + oc0) = uu;
        }
    }
}

// ---- conv3: 32->3 k3 s1 p1 + sigmoid; in h2p NHWC bf16 padded 258x258 ----
__global__ __launch_bounds__(256) void conv3_kernel(const u16* __restrict__ in,
        const float* __restrict__ w, const float* __restrict__ bias,
        float* __restrict__ out) {
    int t = blockIdx.x * 256 + threadIdx.x;    // G*256*256
    int x = t & 255, y = (t >> 8) & 255, b = t >> 16;
    float a0 = bias[0], a1 = bias[1], a2 = bias[2];
    #pragma unroll
    for (int dy = 0; dy < 3; ++dy)
        #pragma unroll
        for (int dx = 0; dx < 3; ++dx) {
            const u16* p = in + ((size_t)(b * 258 + y + dy) * 258 + x + dx) * 32;
            int k = dy * 3 + dx;
            #pragma unroll
            for (int vv = 0; vv < 4; ++vv) {
                short8 s8 = *(const short8*)(p + vv * 8);
                #pragma unroll
                for (int j = 0; j < 8; ++j) {
                    float val = bf2f((u16)s8[j]);
                    int ic = vv * 8 + j;
                    a0 = fmaf(val, w[(0 * 32 + ic) * 9 + k], a0);
                    a1 = fmaf(val, w[(1 * 32 + ic) * 9 + k], a1);
                    a2 = fmaf(val, w[(2 * 32 + ic) * 9 + k], a2);
                }
            }
        }
    float* ob = out + (size_t)b * 196608 + (size_t)y * 256 + x;
    ob[0]      = 1.f / (1.f + expf(-a0));
    ob[65536]  = 1.f / (1.f + expf(-a1));
    ob[131072] = 1.f / (1.f + expf(-a2));
}

// ---------------- launch ----------------
extern "C" void kernel_launch(void* const* d_in, const int* in_sizes, int n_in,
                              void* d_out, int out_size, void* d_ws, size_t ws_size,
                              hipStream_t stream) {
    (void)in_sizes; (void)n_in; (void)out_size;
    const float* x   = (const float*)d_in[0];
    const float* e1w = (const float*)d_in[1];
    const float* e1b = (const float*)d_in[2];
    const float* e2w = (const float*)d_in[3];
    const float* e2b = (const float*)d_in[4];
    const float* emb = (const float*)d_in[5];
    const float* d1w = (const float*)d_in[6];
    const float* d1b = (const float*)d_in[7];
    const float* d2w = (const float*)d_in[8];
    const float* d2b = (const float*)d_in[9];
    const float* d3w = (const float*)d_in[10];
    const float* d3b = (const float*)d_in[11];

    float* out   = (float*)d_out;
    float* recon = out;                    // 6291456 floats
    float* loss  = out + 6291456;          // 1 float
    float* q     = out + 6291457;          // 8388608 floats (4B-aligned only)

    char* wsb = (char*)d_ws;
    u16*   wt1b = (u16*)(wsb + 0);         // 4*64*256 bf16 = 131072 B
    u16*   wt2b = (u16*)(wsb + 131072);    // 4*32*256 bf16 = 65536 B
    u16*   wc2b = (u16*)(wsb + 196608);    // 64*512 bf16   = 65536 B
    float* e2v  = (float*)(wsb + 262144);  // 512 f
    float* prt  = (float*)(wsb + 264192);  // 2048 f
    char*  big  = wsb + 524288;

    // encoder buffers (full batch): z1p 35,145,728 B; z 33,554,432 B
    u16*   z1p = (u16*)big;
    float* zf  = (float*)(big + 35145728);
    // decoder buffers (dq full batch; h1p/h2p grouped)
    u16* dq = (u16*)big;                   // 17,842,176 B (z1p dead by then)

    size_t avail = ws_size > (size_t)524288 ? ws_size - 524288 : 0;
    int G = 32;
    while (G > 1 && (size_t)17842176 + (size_t)G * 6423296 > avail) G >>= 1;
    int ngrp = BB / G;
    u16* h1p = (u16*)(big + 17842176);
    u16* h2p = (u16*)(big + 17842176 + (size_t)G * 2163200);

    // weight prep
    wt_deconv<64, 64><<<256, 256, 0, stream>>>(d1w, wt1b);
    wt_deconv<64, 32><<<128, 256, 0, stream>>>(d2w, wt2b);
    wt_conv2<<<128, 256, 0, stream>>>(e2w, wc2b);
    e2_kernel<<<8, 64, 0, stream>>>(emb, e2v);

    // encoder (full batch)
    border_zero<32, 131, 131, 128, 128><<<2146, 256, 0, stream>>>(z1p, 32);
    conv1_kernel<<<2048, 256, 0, stream>>>(x, e1w, e1b, z1p);
    conv2_mfma<<<1024, 256, 0, stream>>>(z1p, wc2b, e2b, zf);
    vq_kernel<<<512, 256, 0, stream>>>(zf, emb, e2v, q);
    loss_tr<<<2048, 256, 0, stream>>>(q, zf, prt);

    // decoder
    border_zero<64, 66, 66, 64, 64><<<545, 256, 0, stream>>>(dq, 32);
    q_transpose<<<512, 256, 0, stream>>>(q, dq);
    border_zero<64, 130, 130, 128, 128><<<(G * 16900 + 255) / 256, 256, 0, stream>>>(h1p, G);
    border_zero<32, 258, 258, 256, 256><<<(G * 66564 + 255) / 256, 256, 0, stream>>>(h2p, G);
    for (int g = 0; g < ngrp; ++g) {
        u16* dqg = dq + (size_t)g * G * 278784;
        deconv_mfma<64, 64, 64>
            <<<dim3(G * 32, 4), 256, 0, stream>>>(dqg, wt1b, d1b, h1p);
        deconv_mfma<32, 128, 128>
            <<<dim3(G * 128, 4), 256, 0, stream>>>(h1p, wt2b, d2b, h2p);
        conv3_kernel<<<G * 256, 256, 0, stream>>>(h2p, d3w, d3b,
                                                  recon + (size_t)g * G * 196608);
    }
    loss_final<<<1, 256, 0, stream>>>(prt, loss, 1.25f / (float)NZ);
}

// Round 6
// 1000.359 us; speedup vs baseline: 4.0657x; 1.3080x over previous
//
#include <hip/hip_runtime.h>
#include <math.h>

// ---------------- problem constants ----------------
#define BB    32
#define C_IN  3
#define H0    256
#define W0    256
#define C1    32
#define H1    128
#define W1    128
#define C2    64
#define H2    64
#define W2    64
#define HW2   (H2*W2)     // 4096
#define N_EMB 512
#define E_DIM 64
#define NZ    (BB*C2*HW2) // 8388608

typedef unsigned short u16;
typedef unsigned int   uint;
typedef __attribute__((ext_vector_type(8))) short short8;
typedef __attribute__((ext_vector_type(4))) float f32x4;

__device__ inline u16 f2bf(float f) {
    uint u = __builtin_bit_cast(uint, f);
    u += 0x7FFF + ((u >> 16) & 1);          // RNE
    return (u16)(u >> 16);
}
__device__ inline float bf2f(u16 h) {
    uint u = (uint)h << 16;
    return __builtin_bit_cast(float, u);
}
__device__ inline f32x4 mfma16(short8 a, short8 b, f32x4 c) {
    return __builtin_amdgcn_mfma_f32_16x16x32_bf16(a, b, c, 0, 0, 0);
}

// ---- zero the halo border of an NHWC padded buffer (interior at (1,1)) ----
template<int C, int HP, int WP, int H, int W>
__global__ __launch_bounds__(256) void border_zero(u16* buf, int nimg) {
    int t = blockIdx.x * 256 + threadIdx.x;
    if (t >= nimg * HP * WP) return;
    int x = t % WP, y = (t / WP) % HP;
    if (y >= 1 && y < 1 + H && x >= 1 && x < 1 + W) return;
    uint4 z4; z4.x = 0; z4.y = 0; z4.z = 0; z4.w = 0;
    uint4* p = (uint4*)(buf + (size_t)t * C);
    #pragma unroll
    for (int i = 0; i < C / 8; ++i) p[i] = z4;
}

// ---- weight prep: deconv (CI,CO,4,4) fp32 -> bf16 [cls][oc][t*CI+ic] ----
template<int CI, int CO>
__global__ __launch_bounds__(256) void wt_deconv(const float* __restrict__ w,
        u16* __restrict__ wb) {
    int i = blockIdx.x * 256 + threadIdx.x;
    if (i >= 4 * CO * 4 * CI) return;
    int ic  = i % CI;
    int t   = (i / CI) & 3;
    int oc  = (i / (CI * 4)) % CO;
    int cls = i / (CI * 4 * CO);
    int py = cls >> 1, px = cls & 1, ty = t >> 1, tx = t & 1;
    int ky = py ? (ty ? 0 : 2) : (ty ? 3 : 1);
    int kx = px ? (tx ? 0 : 2) : (tx ? 3 : 1);
    wb[i] = f2bf(w[(((size_t)ic * CO + oc) * 4 + ky) * 4 + kx]);
}

// ---- weight prep: conv2 (64,32,4,4) fp32 -> bf16 [oc][tap*32+ic] ----
__global__ __launch_bounds__(256) void wt_conv2(const float* __restrict__ w,
        u16* __restrict__ wb) {
    int i = blockIdx.x * 256 + threadIdx.x;
    if (i >= 64 * 512) return;
    int ic = i & 31;
    int k  = (i >> 5) & 15;
    int oc = i >> 9;
    wb[i] = f2bf(w[(size_t)(oc * 32 + ic) * 16 + k]);
}

// ---- weight prep: conv3 (3,32,3,3) fp32 -> split-bf16 [hi/lo][oc16][tap*32+ic]
// 16 oc rows: rows 0-2 real, 3-15 zero. hi = bf16(w); lo = bf16(w - hi).
__global__ __launch_bounds__(256) void wt_conv3(const float* __restrict__ w,
        u16* __restrict__ wk) {
    int i = blockIdx.x * 256 + threadIdx.x;
    if (i >= 16 * 288) return;
    int ic = i & 31;
    int k  = (i / 32) % 9;
    int oc = i / 288;
    float hi = 0.f, lo = 0.f;
    if (oc < 3) {
        float v = w[(size_t)(oc * 32 + ic) * 9 + k];
        hi = bf2f(f2bf(v));
        lo = v - hi;
    }
    wk[i]            = f2bf(hi);
    wk[i + 16 * 288] = f2bf(lo);
}

// ---- conv1: 3->32, k4 s2 p1, ReLU; out = NHWC bf16 padded (131x131) ----
__global__ __launch_bounds__(256) void conv1_kernel(const float* __restrict__ x,
        const float* __restrict__ w, const float* __restrict__ bias,
        u16* __restrict__ out) {
    int t = blockIdx.x * 256 + threadIdx.x;           // 32*128*128
    int ox = t & (W1 - 1);
    int oy = (t >> 7) & (H1 - 1);
    int b  = t >> 14;
    const float* xb = x + (size_t)b * (C_IN * H0 * W0);
    float v[48];
    #pragma unroll
    for (int ic = 0; ic < 3; ++ic)
        #pragma unroll
        for (int dy = 0; dy < 4; ++dy) {
            int iy = oy * 2 - 1 + dy;
            #pragma unroll
            for (int dx = 0; dx < 4; ++dx) {
                int ix = ox * 2 - 1 + dx;
                float val = 0.f;
                if ((unsigned)iy < H0 && (unsigned)ix < W0)
                    val = xb[((size_t)ic * H0 + iy) * W0 + ix];
                v[(ic * 4 + dy) * 4 + dx] = val;
            }
        }
    u16 h[32];
    #pragma unroll
    for (int oc = 0; oc < C1; ++oc) {
        float a = bias[oc];
        #pragma unroll
        for (int k = 0; k < 48; ++k) a = fmaf(v[k], w[oc * 48 + k], a);
        h[oc] = f2bf(fmaxf(a, 0.f));
    }
    uint4* dst = (uint4*)(out + ((size_t)(b * 131 + oy + 1) * 131 + ox + 1) * 32);
    #pragma unroll
    for (int i = 0; i < 4; ++i) {
        uint4 u;
        u.x = (uint)h[i*8+0] | ((uint)h[i*8+1] << 16);
        u.y = (uint)h[i*8+2] | ((uint)h[i*8+3] << 16);
        u.z = (uint)h[i*8+4] | ((uint)h[i*8+5] << 16);
        u.w = (uint)h[i*8+6] | ((uint)h[i*8+7] << 16);
        dst[i] = u;
    }
}

// ---- conv2 via MFMA: 32->64 k4 s2; in z1p NHWC bf16 padded; out z NHWC fp32 ----
__global__ __launch_bounds__(256) void conv2_mfma(const u16* __restrict__ z1p,
        const u16* __restrict__ wb, const float* __restrict__ bias,
        float* __restrict__ z) {
    int wid = threadIdx.x >> 6, lane = threadIdx.x & 63;
    int m0 = blockIdx.x * 128 + wid * 32;             // 32 pixels per wave
    int b  = m0 >> 12;
    int y  = (m0 >> 6) & 63;
    int x0 = m0 & 63;
    int l15 = lane & 15, lk = lane >> 4;
    f32x4 acc[2][4] = {};
    int xA = x0 + l15, xB = x0 + 16 + l15;
    for (int ks = 0; ks < 16; ++ks) {
        int dy = ks >> 2, dx = ks & 3;
        int rb = (b * 131 + 2 * y + dy) * 131;
        short8 fbA = *(const short8*)(z1p + ((size_t)(rb + 2 * xA + dx)) * 32 + lk * 8);
        short8 fbB = *(const short8*)(z1p + ((size_t)(rb + 2 * xB + dx)) * 32 + lk * 8);
        #pragma unroll
        for (int f = 0; f < 4; ++f) {
            short8 fa = *(const short8*)(wb + (size_t)(f * 16 + l15) * 512 + ks * 32 + lk * 8);
            acc[0][f] = mfma16(fa, fbA, acc[0][f]);
            acc[1][f] = mfma16(fa, fbB, acc[1][f]);
        }
    }
    #pragma unroll
    for (int p = 0; p < 2; ++p) {
        int pix = m0 + p * 16 + l15;
        #pragma unroll
        for (int f = 0; f < 4; ++f) {
            int oc0 = f * 16 + lk * 4;
            float4 bi = *(const float4*)(bias + oc0);
            float4 r;
            r.x = fmaxf(acc[p][f][0] + bi.x, 0.f);
            r.y = fmaxf(acc[p][f][1] + bi.y, 0.f);
            r.z = fmaxf(acc[p][f][2] + bi.z, 0.f);
            r.w = fmaxf(acc[p][f][3] + bi.w, 0.f);
            *(float4*)(z + (size_t)pix * 64 + oc0) = r;
        }
    }
}

// ---------------- embedding squared norms ----------------
__global__ void e2_kernel(const float* __restrict__ emb, float* __restrict__ e2) {
    int e = blockIdx.x * 64 + threadIdx.x;
    float s = 0.f;
    #pragma unroll
    for (int c = 0; c < E_DIM; ++c) {
        float v = emb[(size_t)e * E_DIM + c];
        s = fmaf(v, v, s);
    }
    e2[e] = s;
}

// ---- VQ: z NHWC fp32; argmin(|e|^2 - 2 z.e); scalar q stores (4B-aligned) ----
__global__ __launch_bounds__(256, 4) void vq_kernel(const float* __restrict__ z,
        const float* __restrict__ emb, const float* __restrict__ e2,
        float* __restrict__ q) {
    int r = blockIdx.x * 256 + threadIdx.x;
    float zv[64];
    const float4* zp4 = (const float4*)(z + (size_t)r * 64);
    #pragma unroll
    for (int k = 0; k < 16; ++k) {
        float4 v4 = zp4[k];
        zv[4*k+0] = v4.x; zv[4*k+1] = v4.y; zv[4*k+2] = v4.z; zv[4*k+3] = v4.w;
    }
    float best = 3.4e38f;
    int bi = 0;
    #pragma unroll 2
    for (int e = 0; e < N_EMB; ++e) {
        const float* ep = emb + (size_t)e * E_DIM;    // uniform -> s_load
        float d0 = 0.f, d1 = 0.f, d2 = 0.f, d3 = 0.f;
        #pragma unroll
        for (int k = 0; k < 16; ++k) {
            d0 = fmaf(zv[4*k+0], ep[4*k+0], d0);
            d1 = fmaf(zv[4*k+1], ep[4*k+1], d1);
            d2 = fmaf(zv[4*k+2], ep[4*k+2], d2);
            d3 = fmaf(zv[4*k+3], ep[4*k+3], d3);
        }
        float score = e2[e] - 2.f * ((d0 + d1) + (d2 + d3));
        if (score < best) { best = score; bi = e; }
    }
    const float4* er = (const float4*)(emb + (size_t)bi * E_DIM);
    float* qp = q + (size_t)r * E_DIM;
    #pragma unroll
    for (int k = 0; k < 16; ++k) {
        float4 ev = er[k];
        qp[4*k+0] = ev.x; qp[4*k+1] = ev.y; qp[4*k+2] = ev.z; qp[4*k+3] = ev.w;
    }
}

// ---- loss with faithful NCHW pairing: q_flat[i] vs z_nchw(i); z stored NHWC ----
__global__ __launch_bounds__(256) void loss_tr(const float* __restrict__ q,
        const float* __restrict__ z, float* __restrict__ part) {
    __shared__ float zt[64 * 65];
    int bh = blockIdx.x;                       // b*64 + h
    size_t zbase = (size_t)bh * 4096;
    for (int j = threadIdx.x; j < 4096; j += 256) {
        int w = j >> 6, c = j & 63;
        zt[w * 65 + c] = z[zbase + j];
    }
    __syncthreads();
    int b = bh >> 6, h = bh & 63;
    int w = threadIdx.x & 63;
    float s = 0.f;
    #pragma unroll
    for (int k = 0; k < 16; ++k) {
        int cc = (threadIdx.x >> 6) + k * 4;
        float qv = q[(size_t)b * 262144 + (size_t)cc * 4096 + h * 64 + w];
        float d = qv - zt[w * 65 + cc];
        s = fmaf(d, d, s);
    }
    #pragma unroll
    for (int off = 32; off; off >>= 1) s += __shfl_down(s, off, 64);
    __shared__ float red[4];
    int lane = threadIdx.x & 63, wid = threadIdx.x >> 6;
    if (lane == 0) red[wid] = s;
    __syncthreads();
    if (threadIdx.x == 0) part[blockIdx.x] = (red[0] + red[1]) + (red[2] + red[3]);
}

__global__ __launch_bounds__(256) void loss_final(const float* __restrict__ part,
        float* __restrict__ loss, float scale) {
    float s = 0.f;
    for (int i = threadIdx.x; i < 2048; i += 256) s += part[i];
    #pragma unroll
    for (int off = 32; off; off >>= 1) s += __shfl_down(s, off, 64);
    __shared__ float red[4];
    int lane = threadIdx.x & 63, wid = threadIdx.x >> 6;
    if (lane == 0) red[wid] = s;
    __syncthreads();
    if (threadIdx.x == 0)
        *loss = ((red[0] + red[1]) + (red[2] + red[3])) * scale;
}

// ---- q (NCHW view of q_flat) -> dq NHWC bf16 padded 66x66 ----
__global__ __launch_bounds__(256) void q_transpose(const float* __restrict__ q,
        u16* __restrict__ dq) {
    int t = blockIdx.x * 256 + threadIdx.x;    // 131072
    int x = t & 63, y = (t >> 6) & 63, b = t >> 12;
    const float* src = q + (size_t)b * 262144 + y * 64 + x;
    u16 h[64];
    #pragma unroll
    for (int ic = 0; ic < 64; ++ic) h[ic] = f2bf(src[(size_t)ic * 4096]);
    uint4* dst = (uint4*)(dq + ((size_t)(b * 66 + y + 1) * 66 + x + 1) * 64);
    #pragma unroll
    for (int i = 0; i < 8; ++i) {
        uint4 u;
        u.x = (uint)h[i*8+0] | ((uint)h[i*8+1] << 16);
        u.y = (uint)h[i*8+2] | ((uint)h[i*8+3] << 16);
        u.z = (uint)h[i*8+4] | ((uint)h[i*8+5] << 16);
        u.w = (uint)h[i*8+6] | ((uint)h[i*8+7] << 16);
        dst[i] = u;
    }
}

// ---- deconv k4 s2 p1 via MFMA, 4 parity classes; CI=64; NHWC bf16 padded ----
template<int CO, int HI, int WI>
__global__ __launch_bounds__(256) void deconv_mfma(const u16* __restrict__ in,
        const u16* __restrict__ wb, const float* __restrict__ bias,
        u16* __restrict__ out) {
    constexpr int HPI = HI + 2, WPI = WI + 2;
    constexpr int HPO = 2 * HI + 2, WPO = 2 * WI + 2;
    constexpr int NF = CO / 16;
    int cls = blockIdx.y;
    int py = cls >> 1, px = cls & 1;
    int sy = py ? 1 : -1, sx = px ? 1 : -1;
    int wid = threadIdx.x >> 6, lane = threadIdx.x & 63;
    int m0 = blockIdx.x * 128 + wid * 32;
    int b = m0 / (HI * WI);
    int rem = m0 % (HI * WI);
    int y = rem / WI, x0 = rem % WI;
    int l15 = lane & 15, lk = lane >> 4;
    f32x4 acc[2][NF] = {};
    for (int ks = 0; ks < 8; ++ks) {
        int t = ks >> 1;
        int dy = (t & 2) ? sy : 0;
        int dx = (t & 1) ? sx : 0;
        int rb = (b * HPI + y + dy + 1) * WPI;
        int co = (ks & 1) * 32 + lk * 8;
        short8 fbA = *(const short8*)(in + (size_t)(rb + x0 + l15 + dx + 1) * 64 + co);
        short8 fbB = *(const short8*)(in + (size_t)(rb + x0 + 16 + l15 + dx + 1) * 64 + co);
        #pragma unroll
        for (int f = 0; f < NF; ++f) {
            short8 fa = *(const short8*)(wb + (size_t)(cls * CO + f * 16 + l15) * 256 + ks * 32 + lk * 8);
            acc[0][f] = mfma16(fa, fbA, acc[0][f]);
            acc[1][f] = mfma16(fa, fbB, acc[1][f]);
        }
    }
    int oy = 2 * y + py + 1;
    #pragma unroll
    for (int p = 0; p < 2; ++p) {
        int ox = 2 * (x0 + p * 16 + l15) + px + 1;
        size_t po = ((size_t)(b * HPO + oy) * WPO + ox) * CO;
        #pragma unroll
        for (int f = 0; f < NF; ++f) {
            int oc0 = f * 16 + lk * 4;
            float4 bi = *(const float4*)(bias + oc0);
            float r0 = fmaxf(acc[p][f][0] + bi.x, 0.f);
            float r1 = fmaxf(acc[p][f][1] + bi.y, 0.f);
            float r2 = fmaxf(acc[p][f][2] + bi.z, 0.f);
            float r3 = fmaxf(acc[p][f][3] + bi.w, 0.f);
            uint2 uu;
            uu.x = (uint)f2bf(r0) | ((uint)f2bf(r1) << 16);
            uu.y = (uint)f2bf(r2) | ((uint)f2bf(r3) << 16);
            *(uint2*)(out + po + oc0) = uu;
        }
    }
}

// ---- conv3 via MFMA: 32->3 k3 s1 p1 + sigmoid; split-bf16 weights ----
// A rows = 16 oc slots (3 real), K = tap*32+ic; B = 16 pixels x 32ch NHWC.
__global__ __launch_bounds__(256) void conv3_mfma(const u16* __restrict__ in,
        const u16* __restrict__ wk, const float* __restrict__ bias,
        float* __restrict__ out) {
    int wid = threadIdx.x >> 6, lane = threadIdx.x & 63;
    int m0 = (blockIdx.x * 4 + wid) * 32;      // 32 px per wave
    int b   = m0 >> 16;
    int rem = m0 & 65535;
    int y   = rem >> 8;
    int x0  = rem & 255;
    int l15 = lane & 15, lk = lane >> 4;
    // preload split A-fragments: 9 taps x {hi,lo}
    short8 fa[9][2];
    #pragma unroll
    for (int ks = 0; ks < 9; ++ks) {
        fa[ks][0] = *(const short8*)(wk + (size_t)l15 * 288 + ks * 32 + lk * 8);
        fa[ks][1] = *(const short8*)(wk + 4608 + (size_t)l15 * 288 + ks * 32 + lk * 8);
    }
    f32x4 acc[2] = {};
    #pragma unroll
    for (int ks = 0; ks < 9; ++ks) {
        int dy = ks / 3, dx = ks % 3;
        int rb = (b * 258 + y + dy) * 258;
        short8 fbA = *(const short8*)(in + (size_t)(rb + x0 + l15 + dx) * 32 + lk * 8);
        short8 fbB = *(const short8*)(in + (size_t)(rb + x0 + 16 + l15 + dx) * 32 + lk * 8);
        acc[0] = mfma16(fa[ks][0], fbA, acc[0]);
        acc[0] = mfma16(fa[ks][1], fbA, acc[0]);
        acc[1] = mfma16(fa[ks][0], fbB, acc[1]);
        acc[1] = mfma16(fa[ks][1], fbB, acc[1]);
    }
    if (lk == 0) {                              // rows 0-3 hold oc 0..3
        #pragma unroll
        for (int p = 0; p < 2; ++p) {
            int px = x0 + p * 16 + l15;
            float* ob = out + (size_t)b * 196608 + (size_t)y * 256 + px;
            ob[0]      = 1.f / (1.f + expf(-(acc[p][0] + bias[0])));
            ob[65536]  = 1.f / (1.f + expf(-(acc[p][1] + bias[1])));
            ob[131072] = 1.f / (1.f + expf(-(acc[p][2] + bias[2])));
        }
    }
}

// ---------------- launch ----------------
extern "C" void kernel_launch(void* const* d_in, const int* in_sizes, int n_in,
                              void* d_out, int out_size, void* d_ws, size_t ws_size,
                              hipStream_t stream) {
    (void)in_sizes; (void)n_in; (void)out_size;
    const float* x   = (const float*)d_in[0];
    const float* e1w = (const float*)d_in[1];
    const float* e1b = (const float*)d_in[2];
    const float* e2w = (const float*)d_in[3];
    const float* e2b = (const float*)d_in[4];
    const float* emb = (const float*)d_in[5];
    const float* d1w = (const float*)d_in[6];
    const float* d1b = (const float*)d_in[7];
    const float* d2w = (const float*)d_in[8];
    const float* d2b = (const float*)d_in[9];
    const float* d3w = (const float*)d_in[10];
    const float* d3b = (const float*)d_in[11];

    float* out   = (float*)d_out;
    float* recon = out;                    // 6291456 floats
    float* loss  = out + 6291456;          // 1 float
    float* q     = out + 6291457;          // 8388608 floats (4B-aligned only)

    char* wsb = (char*)d_ws;
    u16*   wt1b = (u16*)(wsb + 0);         // 131072 B
    u16*   wt2b = (u16*)(wsb + 131072);    // 65536 B
    u16*   wc2b = (u16*)(wsb + 196608);    // 65536 B
    float* e2v  = (float*)(wsb + 262144);  // 512 f
    float* prt  = (float*)(wsb + 264192);  // 2048 f -> ends 272384
    u16*   wk3  = (u16*)(wsb + 272384);    // 2*16*288 bf16 = 18432 B
    char*  big  = wsb + 524288;

    u16*   z1p = (u16*)big;                // 35,145,728 B
    float* zf  = (float*)(big + 35145728); // 33,554,432 B
    u16* dq = (u16*)big;                   // 17,842,176 B (z1p dead by then)

    size_t avail = ws_size > (size_t)524288 ? ws_size - 524288 : 0;
    int G = 32;
    while (G > 1 && (size_t)17842176 + (size_t)G * 6423296 > avail) G >>= 1;
    int ngrp = BB / G;
    u16* h1p = (u16*)(big + 17842176);
    u16* h2p = (u16*)(big + 17842176 + (size_t)G * 2163200);

    // weight prep
    wt_deconv<64, 64><<<256, 256, 0, stream>>>(d1w, wt1b);
    wt_deconv<64, 32><<<128, 256, 0, stream>>>(d2w, wt2b);
    wt_conv2<<<128, 256, 0, stream>>>(e2w, wc2b);
    wt_conv3<<<18, 256, 0, stream>>>(d3w, wk3);
    e2_kernel<<<8, 64, 0, stream>>>(emb, e2v);

    // encoder (full batch)
    border_zero<32, 131, 131, 128, 128><<<2146, 256, 0, stream>>>(z1p, 32);
    conv1_kernel<<<2048, 256, 0, stream>>>(x, e1w, e1b, z1p);
    conv2_mfma<<<1024, 256, 0, stream>>>(z1p, wc2b, e2b, zf);
    vq_kernel<<<512, 256, 0, stream>>>(zf, emb, e2v, q);
    loss_tr<<<2048, 256, 0, stream>>>(q, zf, prt);

    // decoder
    border_zero<64, 66, 66, 64, 64><<<545, 256, 0, stream>>>(dq, 32);
    q_transpose<<<512, 256, 0, stream>>>(q, dq);
    border_zero<64, 130, 130, 128, 128><<<(G * 16900 + 255) / 256, 256, 0, stream>>>(h1p, G);
    border_zero<32, 258, 258, 256, 256><<<(G * 66564 + 255) / 256, 256, 0, stream>>>(h2p, G);
    for (int g = 0; g < ngrp; ++g) {
        u16* dqg = dq + (size_t)g * G * 278784;
        deconv_mfma<64, 64, 64>
            <<<dim3(G * 32, 4), 256, 0, stream>>>(dqg, wt1b, d1b, h1p);
        deconv_mfma<32, 128, 128>
            <<<dim3(G * 128, 4), 256, 0, stream>>>(h1p, wt2b, d2b, h2p);
        conv3_mfma<<<G * 512, 256, 0, stream>>>(h2p, wk3, d3b,
                                                recon + (size_t)g * G * 196608);
    }
    loss_final<<<1, 256, 0, stream>>>(prt, loss, 1.25f / (float)NZ);
}

// Round 7
// 787.403 us; speedup vs baseline: 5.1653x; 1.2705x over previous
//
#include <hip/hip_runtime.h>
#include <math.h>

// ---------------- problem constants ----------------
#define BB    32
#define C_IN  3
#define H0    256
#define W0    256
#define C1    32
#define H1    128
#define W1    128
#define C2    64
#define H2    64
#define W2    64
#define HW2   (H2*W2)     // 4096
#define N_EMB 512
#define E_DIM 64
#define NZ    (BB*C2*HW2) // 8388608
#define NPX   (BB*HW2)    // 131072 pixels in VQ

typedef unsigned short u16;
typedef unsigned int   uint;
typedef __attribute__((ext_vector_type(8))) short short8;
typedef __attribute__((ext_vector_type(4))) float f32x4;

__device__ inline u16 f2bf(float f) {
    uint u = __builtin_bit_cast(uint, f);
    u += 0x7FFF + ((u >> 16) & 1);          // RNE
    return (u16)(u >> 16);
}
__device__ inline float bf2f(u16 h) {
    uint u = (uint)h << 16;
    return __builtin_bit_cast(float, u);
}
__device__ inline f32x4 mfma16(short8 a, short8 b, f32x4 c) {
    return __builtin_amdgcn_mfma_f32_16x16x32_bf16(a, b, c, 0, 0, 0);
}

// ---- zero the halo border of an NHWC padded buffer (interior at (1,1)) ----
template<int C, int HP, int WP, int H, int W>
__global__ __launch_bounds__(256) void border_zero(u16* buf, int nimg) {
    int t = blockIdx.x * 256 + threadIdx.x;
    if (t >= nimg * HP * WP) return;
    int x = t % WP, y = (t / WP) % HP;
    if (y >= 1 && y < 1 + H && x >= 1 && x < 1 + W) return;
    uint4 z4; z4.x = 0; z4.y = 0; z4.z = 0; z4.w = 0;
    uint4* p = (uint4*)(buf + (size_t)t * C);
    #pragma unroll
    for (int i = 0; i < C / 8; ++i) p[i] = z4;
}

// ---- weight prep: deconv (CI,CO,4,4) fp32 -> bf16 [cls][oc][t*CI+ic] ----
template<int CI, int CO>
__global__ __launch_bounds__(256) void wt_deconv(const float* __restrict__ w,
        u16* __restrict__ wb) {
    int i = blockIdx.x * 256 + threadIdx.x;
    if (i >= 4 * CO * 4 * CI) return;
    int ic  = i % CI;
    int t   = (i / CI) & 3;
    int oc  = (i / (CI * 4)) % CO;
    int cls = i / (CI * 4 * CO);
    int py = cls >> 1, px = cls & 1, ty = t >> 1, tx = t & 1;
    int ky = py ? (ty ? 0 : 2) : (ty ? 3 : 1);
    int kx = px ? (tx ? 0 : 2) : (tx ? 3 : 1);
    wb[i] = f2bf(w[(((size_t)ic * CO + oc) * 4 + ky) * 4 + kx]);
}

// ---- weight prep: conv2 (64,32,4,4) fp32 -> bf16 [oc][tap*32+ic] ----
__global__ __launch_bounds__(256) void wt_conv2(const float* __restrict__ w,
        u16* __restrict__ wb) {
    int i = blockIdx.x * 256 + threadIdx.x;
    if (i >= 64 * 512) return;
    int ic = i & 31;
    int k  = (i >> 5) & 15;
    int oc = i >> 9;
    wb[i] = f2bf(w[(size_t)(oc * 32 + ic) * 16 + k]);
}

// ---- weight prep: conv3 (3,32,3,3) fp32 -> split-bf16 [hi/lo][oc16][tap*32+ic]
__global__ __launch_bounds__(256) void wt_conv3(const float* __restrict__ w,
        u16* __restrict__ wk) {
    int i = blockIdx.x * 256 + threadIdx.x;
    if (i >= 16 * 288) return;
    int ic = i & 31;
    int k  = (i / 32) % 9;
    int oc = i / 288;
    float hi = 0.f, lo = 0.f;
    if (oc < 3) {
        float v = w[(size_t)(oc * 32 + ic) * 9 + k];
        hi = bf2f(f2bf(v));
        lo = v - hi;
    }
    wk[i]            = f2bf(hi);
    wk[i + 16 * 288] = f2bf(lo);
}

// ---- conv1: 3->32, k4 s2 p1, ReLU; out = NHWC bf16 padded (131x131) ----
__global__ __launch_bounds__(256) void conv1_kernel(const float* __restrict__ x,
        const float* __restrict__ w, const float* __restrict__ bias,
        u16* __restrict__ out) {
    int t = blockIdx.x * 256 + threadIdx.x;           // 32*128*128
    int ox = t & (W1 - 1);
    int oy = (t >> 7) & (H1 - 1);
    int b  = t >> 14;
    const float* xb = x + (size_t)b * (C_IN * H0 * W0);
    float v[48];
    #pragma unroll
    for (int ic = 0; ic < 3; ++ic)
        #pragma unroll
        for (int dy = 0; dy < 4; ++dy) {
            int iy = oy * 2 - 1 + dy;
            #pragma unroll
            for (int dx = 0; dx < 4; ++dx) {
                int ix = ox * 2 - 1 + dx;
                float val = 0.f;
                if ((unsigned)iy < H0 && (unsigned)ix < W0)
                    val = xb[((size_t)ic * H0 + iy) * W0 + ix];
                v[(ic * 4 + dy) * 4 + dx] = val;
            }
        }
    u16 h[32];
    #pragma unroll
    for (int oc = 0; oc < C1; ++oc) {
        float a = bias[oc];
        #pragma unroll
        for (int k = 0; k < 48; ++k) a = fmaf(v[k], w[oc * 48 + k], a);
        h[oc] = f2bf(fmaxf(a, 0.f));
    }
    uint4* dst = (uint4*)(out + ((size_t)(b * 131 + oy + 1) * 131 + ox + 1) * 32);
    #pragma unroll
    for (int i = 0; i < 4; ++i) {
        uint4 u;
        u.x = (uint)h[i*8+0] | ((uint)h[i*8+1] << 16);
        u.y = (uint)h[i*8+2] | ((uint)h[i*8+3] << 16);
        u.z = (uint)h[i*8+4] | ((uint)h[i*8+5] << 16);
        u.w = (uint)h[i*8+6] | ((uint)h[i*8+7] << 16);
        dst[i] = u;
    }
}

// ---- conv2 via MFMA: 32->64 k4 s2; in z1p NHWC bf16 padded; out z NHWC fp32 ----
__global__ __launch_bounds__(256) void conv2_mfma(const u16* __restrict__ z1p,
        const u16* __restrict__ wb, const float* __restrict__ bias,
        float* __restrict__ z) {
    int wid = threadIdx.x >> 6, lane = threadIdx.x & 63;
    int m0 = blockIdx.x * 128 + wid * 32;             // 32 pixels per wave
    int b  = m0 >> 12;
    int y  = (m0 >> 6) & 63;
    int x0 = m0 & 63;
    int l15 = lane & 15, lk = lane >> 4;
    f32x4 acc[2][4] = {};
    int xA = x0 + l15, xB = x0 + 16 + l15;
    for (int ks = 0; ks < 16; ++ks) {
        int dy = ks >> 2, dx = ks & 3;
        int rb = (b * 131 + 2 * y + dy) * 131;
        short8 fbA = *(const short8*)(z1p + ((size_t)(rb + 2 * xA + dx)) * 32 + lk * 8);
        short8 fbB = *(const short8*)(z1p + ((size_t)(rb + 2 * xB + dx)) * 32 + lk * 8);
        #pragma unroll
        for (int f = 0; f < 4; ++f) {
            short8 fa = *(const short8*)(wb + (size_t)(f * 16 + l15) * 512 + ks * 32 + lk * 8);
            acc[0][f] = mfma16(fa, fbA, acc[0][f]);
            acc[1][f] = mfma16(fa, fbB, acc[1][f]);
        }
    }
    #pragma unroll
    for (int p = 0; p < 2; ++p) {
        int pix = m0 + p * 16 + l15;
        #pragma unroll
        for (int f = 0; f < 4; ++f) {
            int oc0 = f * 16 + lk * 4;
            float4 bi = *(const float4*)(bias + oc0);
            float4 r;
            r.x = fmaxf(acc[p][f][0] + bi.x, 0.f);
            r.y = fmaxf(acc[p][f][1] + bi.y, 0.f);
            r.z = fmaxf(acc[p][f][2] + bi.z, 0.f);
            r.w = fmaxf(acc[p][f][3] + bi.w, 0.f);
            *(float4*)(z + (size_t)pix * 64 + oc0) = r;
        }
    }
}

// ---------------- embedding squared norms ----------------
__global__ void e2_kernel(const float* __restrict__ emb, float* __restrict__ e2) {
    int e = blockIdx.x * 64 + threadIdx.x;
    float s = 0.f;
    #pragma unroll
    for (int c = 0; c < E_DIM; ++c) {
        float v = emb[(size_t)e * E_DIM + c];
        s = fmaf(v, v, s);
    }
    e2[e] = s;
}

// ---- VQ part: each block scans 128 embeddings for 256 pixels ----
// blockIdx.x = tile*4 + part; writes per-pixel (best score, index).
__global__ __launch_bounds__(256) void vq_part(const float* __restrict__ z,
        const float* __restrict__ emb, const float* __restrict__ e2,
        float* __restrict__ vqs, int* __restrict__ vqi) {
    int tile = blockIdx.x >> 2;
    int part = blockIdx.x & 3;
    int r = tile * 256 + threadIdx.x;
    float zv[64];
    const float4* zp4 = (const float4*)(z + (size_t)r * 64);
    #pragma unroll
    for (int k = 0; k < 16; ++k) {
        float4 v4 = zp4[k];
        zv[4*k+0] = v4.x; zv[4*k+1] = v4.y; zv[4*k+2] = v4.z; zv[4*k+3] = v4.w;
    }
    int e0 = part * 128;
    float best = 3.4e38f;
    int bi = e0;
    #pragma unroll 2
    for (int e = e0; e < e0 + 128; ++e) {
        const float* ep = emb + (size_t)e * E_DIM;    // uniform -> s_load
        float d0 = 0.f, d1 = 0.f, d2 = 0.f, d3 = 0.f;
        #pragma unroll
        for (int k = 0; k < 16; ++k) {
            d0 = fmaf(zv[4*k+0], ep[4*k+0], d0);
            d1 = fmaf(zv[4*k+1], ep[4*k+1], d1);
            d2 = fmaf(zv[4*k+2], ep[4*k+2], d2);
            d3 = fmaf(zv[4*k+3], ep[4*k+3], d3);
        }
        float score = e2[e] - 2.f * ((d0 + d1) + (d2 + d3));
        if (score < best) { best = score; bi = e; }
    }
    vqs[(size_t)part * NPX + r] = best;
    vqi[(size_t)part * NPX + r] = bi;
}

// ---- VQ reduce: 4-way min (ascending part order = first-min tie rule) + gather ----
__global__ __launch_bounds__(256) void vq_reduce(const float* __restrict__ vqs,
        const int* __restrict__ vqi, const float* __restrict__ emb,
        float* __restrict__ q) {
    int r = blockIdx.x * 256 + threadIdx.x;
    float best = vqs[r];
    int bi = vqi[r];
    #pragma unroll
    for (int p = 1; p < 4; ++p) {
        float s = vqs[(size_t)p * NPX + r];
        int i2 = vqi[(size_t)p * NPX + r];
        if (s < best) { best = s; bi = i2; }
    }
    const float4* er = (const float4*)(emb + (size_t)bi * E_DIM);
    float* qp = q + (size_t)r * E_DIM;        // 4B-aligned only: scalar stores
    #pragma unroll
    for (int k = 0; k < 16; ++k) {
        float4 ev = er[k];
        qp[4*k+0] = ev.x; qp[4*k+1] = ev.y; qp[4*k+2] = ev.z; qp[4*k+3] = ev.w;
    }
}

// ---- loss with faithful NCHW pairing: q_flat[i] vs z_nchw(i); z stored NHWC ----
__global__ __launch_bounds__(256) void loss_tr(const float* __restrict__ q,
        const float* __restrict__ z, float* __restrict__ part) {
    __shared__ float zt[64 * 65];
    int bh = blockIdx.x;                       // b*64 + h
    size_t zbase = (size_t)bh * 4096;
    for (int j = threadIdx.x; j < 4096; j += 256) {
        int w = j >> 6, c = j & 63;
        zt[w * 65 + c] = z[zbase + j];
    }
    __syncthreads();
    int b = bh >> 6, h = bh & 63;
    int w = threadIdx.x & 63;
    float s = 0.f;
    #pragma unroll
    for (int k = 0; k < 16; ++k) {
        int cc = (threadIdx.x >> 6) + k * 4;
        float qv = q[(size_t)b * 262144 + (size_t)cc * 4096 + h * 64 + w];
        float d = qv - zt[w * 65 + cc];
        s = fmaf(d, d, s);
    }
    #pragma unroll
    for (int off = 32; off; off >>= 1) s += __shfl_down(s, off, 64);
    __shared__ float red[4];
    int lane = threadIdx.x & 63, wid = threadIdx.x >> 6;
    if (lane == 0) red[wid] = s;
    __syncthreads();
    if (threadIdx.x == 0) part[blockIdx.x] = (red[0] + red[1]) + (red[2] + red[3]);
}

__global__ __launch_bounds__(256) void loss_final(const float* __restrict__ part,
        float* __restrict__ loss, float scale) {
    float s = 0.f;
    for (int i = threadIdx.x; i < 2048; i += 256) s += part[i];
    #pragma unroll
    for (int off = 32; off; off >>= 1) s += __shfl_down(s, off, 64);
    __shared__ float red[4];
    int lane = threadIdx.x & 63, wid = threadIdx.x >> 6;
    if (lane == 0) red[wid] = s;
    __syncthreads();
    if (threadIdx.x == 0)
        *loss = ((red[0] + red[1]) + (red[2] + red[3])) * scale;
}

// ---- q (NCHW view of q_flat) -> dq NHWC bf16 padded 66x66 ----
__global__ __launch_bounds__(256) void q_transpose(const float* __restrict__ q,
        u16* __restrict__ dq) {
    int t = blockIdx.x * 256 + threadIdx.x;    // 131072
    int x = t & 63, y = (t >> 6) & 63, b = t >> 12;
    const float* src = q + (size_t)b * 262144 + y * 64 + x;
    u16 h[64];
    #pragma unroll
    for (int ic = 0; ic < 64; ++ic) h[ic] = f2bf(src[(size_t)ic * 4096]);
    uint4* dst = (uint4*)(dq + ((size_t)(b * 66 + y + 1) * 66 + x + 1) * 64);
    #pragma unroll
    for (int i = 0; i < 8; ++i) {
        uint4 u;
        u.x = (uint)h[i*8+0] | ((uint)h[i*8+1] << 16);
        u.y = (uint)h[i*8+2] | ((uint)h[i*8+3] << 16);
        u.z = (uint)h[i*8+4] | ((uint)h[i*8+5] << 16);
        u.w = (uint)h[i*8+6] | ((uint)h[i*8+7] << 16);
        dst[i] = u;
    }
}

// ---- deconv k4 s2 p1 via MFMA, 4 parity classes; CI=64; NHWC bf16 padded ----
template<int CO, int HI, int WI>
__global__ __launch_bounds__(256) void deconv_mfma(const u16* __restrict__ in,
        const u16* __restrict__ wb, const float* __restrict__ bias,
        u16* __restrict__ out) {
    constexpr int HPI = HI + 2, WPI = WI + 2;
    constexpr int HPO = 2 * HI + 2, WPO = 2 * WI + 2;
    constexpr int NF = CO / 16;
    int cls = blockIdx.y;
    int py = cls >> 1, px = cls & 1;
    int sy = py ? 1 : -1, sx = px ? 1 : -1;
    int wid = threadIdx.x >> 6, lane = threadIdx.x & 63;
    int m0 = blockIdx.x * 128 + wid * 32;
    int b = m0 / (HI * WI);
    int rem = m0 % (HI * WI);
    int y = rem / WI, x0 = rem % WI;
    int l15 = lane & 15, lk = lane >> 4;
    f32x4 acc[2][NF] = {};
    for (int ks = 0; ks < 8; ++ks) {
        int t = ks >> 1;
        int dy = (t & 2) ? sy : 0;
        int dx = (t & 1) ? sx : 0;
        int rb = (b * HPI + y + dy + 1) * WPI;
        int co = (ks & 1) * 32 + lk * 8;
        short8 fbA = *(const short8*)(in + (size_t)(rb + x0 + l15 + dx + 1) * 64 + co);
        short8 fbB = *(const short8*)(in + (size_t)(rb + x0 + 16 + l15 + dx + 1) * 64 + co);
        #pragma unroll
        for (int f = 0; f < NF; ++f) {
            short8 fa = *(const short8*)(wb + (size_t)(cls * CO + f * 16 + l15) * 256 + ks * 32 + lk * 8);
            acc[0][f] = mfma16(fa, fbA, acc[0][f]);
            acc[1][f] = mfma16(fa, fbB, acc[1][f]);
        }
    }
    int oy = 2 * y + py + 1;
    #pragma unroll
    for (int p = 0; p < 2; ++p) {
        int ox = 2 * (x0 + p * 16 + l15) + px + 1;
        size_t po = ((size_t)(b * HPO + oy) * WPO + ox) * CO;
        #pragma unroll
        for (int f = 0; f < NF; ++f) {
            int oc0 = f * 16 + lk * 4;
            float4 bi = *(const float4*)(bias + oc0);
            float r0 = fmaxf(acc[p][f][0] + bi.x, 0.f);
            float r1 = fmaxf(acc[p][f][1] + bi.y, 0.f);
            float r2 = fmaxf(acc[p][f][2] + bi.z, 0.f);
            float r3 = fmaxf(acc[p][f][3] + bi.w, 0.f);
            uint2 uu;
            uu.x = (uint)f2bf(r0) | ((uint)f2bf(r1) << 16);
            uu.y = (uint)f2bf(r2) | ((uint)f2bf(r3) << 16);
            *(uint2*)(out + po + oc0) = uu;
        }
    }
}

// ---- conv3 via MFMA: 32->3 k3 s1 p1 + sigmoid; split-bf16 weights ----
__global__ __launch_bounds__(256) void conv3_mfma(const u16* __restrict__ in,
        const u16* __restrict__ wk, const float* __restrict__ bias,
        float* __restrict__ out) {
    int wid = threadIdx.x >> 6, lane = threadIdx.x & 63;
    int m0 = (blockIdx.x * 4 + wid) * 32;      // 32 px per wave
    int b   = m0 >> 16;
    int rem = m0 & 65535;
    int y   = rem >> 8;
    int x0  = rem & 255;
    int l15 = lane & 15, lk = lane >> 4;
    short8 fa[9][2];
    #pragma unroll
    for (int ks = 0; ks < 9; ++ks) {
        fa[ks][0] = *(const short8*)(wk + (size_t)l15 * 288 + ks * 32 + lk * 8);
        fa[ks][1] = *(const short8*)(wk + 4608 + (size_t)l15 * 288 + ks * 32 + lk * 8);
    }
    f32x4 acc[2] = {};
    #pragma unroll
    for (int ks = 0; ks < 9; ++ks) {
        int dy = ks / 3, dx = ks % 3;
        int rb = (b * 258 + y + dy) * 258;
        short8 fbA = *(const short8*)(in + (size_t)(rb + x0 + l15 + dx) * 32 + lk * 8);
        short8 fbB = *(const short8*)(in + (size_t)(rb + x0 + 16 + l15 + dx) * 32 + lk * 8);
        acc[0] = mfma16(fa[ks][0], fbA, acc[0]);
        acc[0] = mfma16(fa[ks][1], fbA, acc[0]);
        acc[1] = mfma16(fa[ks][0], fbB, acc[1]);
        acc[1] = mfma16(fa[ks][1], fbB, acc[1]);
    }
    if (lk == 0) {
        #pragma unroll
        for (int p = 0; p < 2; ++p) {
            int px = x0 + p * 16 + l15;
            float* ob = out + (size_t)b * 196608 + (size_t)y * 256 + px;
            ob[0]      = 1.f / (1.f + expf(-(acc[p][0] + bias[0])));
            ob[65536]  = 1.f / (1.f + expf(-(acc[p][1] + bias[1])));
            ob[131072] = 1.f / (1.f + expf(-(acc[p][2] + bias[2])));
        }
    }
}

// ---------------- launch ----------------
extern "C" void kernel_launch(void* const* d_in, const int* in_sizes, int n_in,
                              void* d_out, int out_size, void* d_ws, size_t ws_size,
                              hipStream_t stream) {
    (void)in_sizes; (void)n_in; (void)out_size;
    const float* x   = (const float*)d_in[0];
    const float* e1w = (const float*)d_in[1];
    const float* e1b = (const float*)d_in[2];
    const float* e2w = (const float*)d_in[3];
    const float* e2b = (const float*)d_in[4];
    const float* emb = (const float*)d_in[5];
    const float* d1w = (const float*)d_in[6];
    const float* d1b = (const float*)d_in[7];
    const float* d2w = (const float*)d_in[8];
    const float* d2b = (const float*)d_in[9];
    const float* d3w = (const float*)d_in[10];
    const float* d3b = (const float*)d_in[11];

    float* out   = (float*)d_out;
    float* recon = out;                    // 6291456 floats
    float* loss  = out + 6291456;          // 1 float
    float* q     = out + 6291457;          // 8388608 floats (4B-aligned only)

    char* wsb = (char*)d_ws;
    u16*   wt1b = (u16*)(wsb + 0);         // 131072 B
    u16*   wt2b = (u16*)(wsb + 131072);    // 65536 B
    u16*   wc2b = (u16*)(wsb + 196608);    // 65536 B
    float* e2v  = (float*)(wsb + 262144);  // 512 f
    float* prt  = (float*)(wsb + 264192);  // 2048 f -> ends 272384
    u16*   wk3  = (u16*)(wsb + 272384);    // 18432 B
    char*  big  = wsb + 524288;

    u16*   z1p = (u16*)big;                     // 35,145,728 B
    float* zf  = (float*)(big + 35145728);      // 33,554,432 B
    // vq partial results live after zf (used between conv2 and decoder)
    float* vqs = (float*)(big + 68700160);      // 4*131072*4 = 2,097,152 B
    int*   vqi = (int*)(big + 70797312);        // 2,097,152 B
    u16* dq = (u16*)big;                        // decoder reuse (z1p dead)

    size_t avail = ws_size > (size_t)524288 ? ws_size - 524288 : 0;
    int G = 32;
    while (G > 1 && (size_t)17842176 + (size_t)G * 6423296 > avail) G >>= 1;
    int ngrp = BB / G;
    u16* h1p = (u16*)(big + 17842176);
    u16* h2p = (u16*)(big + 17842176 + (size_t)G * 2163200);

    // weight prep
    wt_deconv<64, 64><<<256, 256, 0, stream>>>(d1w, wt1b);
    wt_deconv<64, 32><<<128, 256, 0, stream>>>(d2w, wt2b);
    wt_conv2<<<128, 256, 0, stream>>>(e2w, wc2b);
    wt_conv3<<<18, 256, 0, stream>>>(d3w, wk3);
    e2_kernel<<<8, 64, 0, stream>>>(emb, e2v);

    // encoder (full batch)
    border_zero<32, 131, 131, 128, 128><<<2146, 256, 0, stream>>>(z1p, 32);
    conv1_kernel<<<2048, 256, 0, stream>>>(x, e1w, e1b, z1p);
    conv2_mfma<<<1024, 256, 0, stream>>>(z1p, wc2b, e2b, zf);
    vq_part<<<2048, 256, 0, stream>>>(zf, emb, e2v, vqs, vqi);
    vq_reduce<<<512, 256, 0, stream>>>(vqs, vqi, emb, q);
    loss_tr<<<2048, 256, 0, stream>>>(q, zf, prt);

    // decoder
    border_zero<64, 66, 66, 64, 64><<<545, 256, 0, stream>>>(dq, 32);
    q_transpose<<<512, 256, 0, stream>>>(q, dq);
    border_zero<64, 130, 130, 128, 128><<<(G * 16900 + 255) / 256, 256, 0, stream>>>(h1p, G);
    border_zero<32, 258, 258, 256, 256><<<(G * 66564 + 255) / 256, 256, 0, stream>>>(h2p, G);
    for (int g = 0; g < ngrp; ++g) {
        u16* dqg = dq + (size_t)g * G * 278784;
        deconv_mfma<64, 64, 64>
            <<<dim3(G * 32, 4), 256, 0, stream>>>(dqg, wt1b, d1b, h1p);
        deconv_mfma<32, 128, 128>
            <<<dim3(G * 128, 4), 256, 0, stream>>>(h1p, wt2b, d2b, h2p);
        conv3_mfma<<<G * 512, 256, 0, stream>>>(h2p, wk3, d3b,
                                                recon + (size_t)g * G * 196608);
    }
    loss_final<<<1, 256, 0, stream>>>(prt, loss, 1.25f / (float)NZ);
}